// Round 1
// baseline (232.422 us; speedup 1.0000x reference)
//
#include <hip/hip_runtime.h>
#include <hip/hip_bf16.h>
#include <cmath>

typedef __bf16 bf16;
typedef __attribute__((ext_vector_type(8))) __bf16 bf16x8;
typedef __attribute__((ext_vector_type(4))) float f32x4;

// ---------------------------------------------------------------------------
// GEMM: C[M x 512] = A[M x 512] * W[512 x 512] + bias
// MODE 0: A fp32, output bf16 head-split [B,H,S,64]   (QKV projections)
// MODE 1: A bf16, output fp32 flat [M,512]            (final projection)
// 128x128 tile, BK=32, 256 threads (4 waves, 2x2), 16x16x32 bf16 MFMA.
// ---------------------------------------------------------------------------
template<int MODE>
__global__ __launch_bounds__(256)
void gemm_kernel(const void* __restrict__ Ap, const float* __restrict__ W,
                 const float* __restrict__ bias, void* __restrict__ Cp)
{
    const int K = 512, N = 512;
    const int bm = blockIdx.x;           // M/128
    const int bn = blockIdx.y;           // N/128 = 4
    const int tid = threadIdx.x;
    const int wave = tid >> 6, lane = tid & 63;
    const int wr = wave >> 1, wc = wave & 1;        // 2x2 waves -> 64x64 each
    const int g = lane >> 4, r = lane & 15;

    // pad 32 -> 56 elems (112B rows: 16B-aligned, 2-way-max bank aliasing)
    __shared__ bf16 As[128][56];
    __shared__ bf16 Bs[128][56];         // transposed: Bs[n][k] = W[kt+k][col0+n]

    f32x4 acc[4][4] = {};
    const int row0 = bm * 128;
    const int col0 = bn * 128;

    for (int kt = 0; kt < K; kt += 32) {
        // ---- stage A tile: 128 rows x 32 k ----
        {
            const int arow = tid >> 1;
            const int k0 = (tid & 1) * 16;
            if (MODE == 0) {
                const float* A = (const float*)Ap;
                const float* src = A + (size_t)(row0 + arow) * K + kt + k0;
                f32x4 f0 = *(const f32x4*)(src);
                f32x4 f1 = *(const f32x4*)(src + 4);
                f32x4 f2 = *(const f32x4*)(src + 8);
                f32x4 f3 = *(const f32x4*)(src + 12);
                bf16x8 v0, v1;
#pragma unroll
                for (int i = 0; i < 4; i++) {
                    v0[i] = (bf16)f0[i]; v0[4+i] = (bf16)f1[i];
                    v1[i] = (bf16)f2[i]; v1[4+i] = (bf16)f3[i];
                }
                *(bf16x8*)&As[arow][k0]     = v0;
                *(bf16x8*)&As[arow][k0 + 8] = v1;
            } else {
                const bf16* A = (const bf16*)Ap;
                const bf16* src = A + (size_t)(row0 + arow) * K + kt + k0;
                *(bf16x8*)&As[arow][k0]     = *(const bf16x8*)(src);
                *(bf16x8*)&As[arow][k0 + 8] = *(const bf16x8*)(src + 8);
            }
        }
        // ---- stage B tile transposed: 32 k-rows x 128 n-cols ----
        {
            const int krow = tid >> 3;           // 0..31
            const int n0 = (tid & 7) * 16;
            const float* src = W + (size_t)(kt + krow) * N + col0 + n0;
#pragma unroll
            for (int c = 0; c < 16; c += 4) {
                f32x4 f = *(const f32x4*)(src + c);
                Bs[n0 + c + 0][krow] = (bf16)f[0];
                Bs[n0 + c + 1][krow] = (bf16)f[1];
                Bs[n0 + c + 2][krow] = (bf16)f[2];
                Bs[n0 + c + 3][krow] = (bf16)f[3];
            }
        }
        __syncthreads();

        bf16x8 af[4], bfr[4];
#pragma unroll
        for (int mf = 0; mf < 4; mf++)
            af[mf] = *(const bf16x8*)&As[wr*64 + mf*16 + r][g*8];
#pragma unroll
        for (int nf = 0; nf < 4; nf++)
            bfr[nf] = *(const bf16x8*)&Bs[wc*64 + nf*16 + r][g*8];
#pragma unroll
        for (int mf = 0; mf < 4; mf++)
#pragma unroll
            for (int nf = 0; nf < 4; nf++)
                acc[mf][nf] = __builtin_amdgcn_mfma_f32_16x16x32_bf16(
                    af[mf], bfr[nf], acc[mf][nf], 0, 0, 0);
        __syncthreads();
    }

    // ---- epilogue ----
#pragma unroll
    for (int mf = 0; mf < 4; mf++) {
#pragma unroll
        for (int nf = 0; nf < 4; nf++) {
#pragma unroll
            for (int j = 0; j < 4; j++) {
                const int rrow = row0 + wr*64 + mf*16 + g*4 + j;
                const int ccol = col0 + wc*64 + nf*16 + r;
                const float val = acc[mf][nf][j] + bias[ccol];
                if (MODE == 0) {
                    bf16* C = (bf16*)Cp;
                    const int b = rrow >> 11, s = rrow & 2047;
                    const int h = ccol >> 6, hd = ccol & 63;
                    C[(((size_t)(b*8 + h) * 2048) + s) * 64 + hd] = (bf16)val;
                } else {
                    float* C = (float*)Cp;
                    C[(size_t)rrow * 512 + ccol] = val;
                }
            }
        }
    }
}

// ---------------------------------------------------------------------------
// Flash attention: per block one (b,h) and a 128-query tile.
// 4 waves x 32 q-rows; K/V tiles of 64 keys; online softmax in fp32.
// qp/kp/vp: bf16 [B,H,S,64]; mask: int [B,S]; out: bf16 [B,S,512] merged.
// ---------------------------------------------------------------------------
__global__ __launch_bounds__(256)
void attn_kernel(const bf16* __restrict__ qp, const bf16* __restrict__ kp,
                 const bf16* __restrict__ vp, const int* __restrict__ mask,
                 bf16* __restrict__ attn)
{
    const int bh = blockIdx.x;           // 0..31
    const int qt = blockIdx.y;           // 0..15
    const int b = bh >> 3, h = bh & 7;
    const int tid = threadIdx.x;
    const int w = tid >> 6, lane = tid & 63;
    const int g = lane >> 4, r = lane & 15;

    __shared__ bf16 Qs[128][72];         // [q][hd], pad 64->72 (144B rows)
    __shared__ bf16 Ks[64][72];          // [key][hd]
    __shared__ bf16 Vt[64][72];          // [hd][key]  (transposed)
    __shared__ bf16 Ps[128][72];         // [q][key]
    __shared__ float maskadd[64];

    const size_t head_base = (size_t)(b*8 + h) * 2048 * 64;
    const int q0 = qt * 128;

    // ---- load Q tile once ----
    {
        const int row = tid >> 1;
        const int c0 = (tid & 1) * 32;
        const bf16* src = qp + head_base + (size_t)(q0 + row) * 64 + c0;
#pragma unroll
        for (int i = 0; i < 32; i += 8)
            *(bf16x8*)&Qs[row][c0 + i] = *(const bf16x8*)(src + i);
    }
    __syncthreads();

    bf16x8 qf[2][2];
#pragma unroll
    for (int qi = 0; qi < 2; qi++)
#pragma unroll
        for (int ks = 0; ks < 2; ks++)
            qf[qi][ks] = *(const bf16x8*)&Qs[w*32 + qi*16 + r][ks*32 + g*8];

    float m_run[2][4], l_run[2][4];
    f32x4 o_acc[2][4] = {};
#pragma unroll
    for (int qi = 0; qi < 2; qi++)
#pragma unroll
        for (int j = 0; j < 4; j++) { m_run[qi][j] = -INFINITY; l_run[qi][j] = 0.f; }

    for (int kt = 0; kt < 2048; kt += 64) {
        // ---- stage K tile [64 keys][64 hd] ----
        {
            const int row = tid >> 2;
            const int c0 = (tid & 3) * 16;
            const bf16* src = kp + head_base + (size_t)(kt + row) * 64 + c0;
            *(bf16x8*)&Ks[row][c0]     = *(const bf16x8*)(src);
            *(bf16x8*)&Ks[row][c0 + 8] = *(const bf16x8*)(src + 8);
        }
        // ---- stage V transposed -> Vt[hd][key] ----
        {
            const int row = tid >> 2;
            const int c0 = (tid & 3) * 16;
            const bf16* src = vp + head_base + (size_t)(kt + row) * 64 + c0;
            bf16x8 v0 = *(const bf16x8*)(src);
            bf16x8 v1 = *(const bf16x8*)(src + 8);
#pragma unroll
            for (int i = 0; i < 8; i++) {
                Vt[c0 + i][row]     = v0[i];
                Vt[c0 + 8 + i][row] = v1[i];
            }
        }
        if (tid < 64) maskadd[tid] = -1e9f * (float)mask[b * 2048 + kt + tid];
        __syncthreads();

        // ---- scores = Q * K^T ----
        f32x4 sa[2][4] = {};
#pragma unroll
        for (int ks = 0; ks < 2; ks++) {
            bf16x8 kfrag[4];
#pragma unroll
            for (int kf = 0; kf < 4; kf++)
                kfrag[kf] = *(const bf16x8*)&Ks[kf*16 + r][ks*32 + g*8];
#pragma unroll
            for (int qi = 0; qi < 2; qi++)
#pragma unroll
                for (int kf = 0; kf < 4; kf++)
                    sa[qi][kf] = __builtin_amdgcn_mfma_f32_16x16x32_bf16(
                        qf[qi][ks], kfrag[kf], sa[qi][kf], 0, 0, 0);
        }

        // ---- online softmax (rows in C-layout: row = g*4+j) ----
        float madd[4];
#pragma unroll
        for (int kf = 0; kf < 4; kf++) madd[kf] = maskadd[kf*16 + r];
#pragma unroll
        for (int qi = 0; qi < 2; qi++) {
#pragma unroll
            for (int j = 0; j < 4; j++) {
                float v0 = sa[qi][0][j] * 0.125f + madd[0];
                float v1 = sa[qi][1][j] * 0.125f + madd[1];
                float v2 = sa[qi][2][j] * 0.125f + madd[2];
                float v3 = sa[qi][3][j] * 0.125f + madd[3];
                float mx = fmaxf(fmaxf(v0, v1), fmaxf(v2, v3));
#pragma unroll
                for (int sh = 1; sh < 16; sh <<= 1) mx = fmaxf(mx, __shfl_xor(mx, sh, 64));
                const float m_new = fmaxf(m_run[qi][j], mx);
                const float corr = __expf(m_run[qi][j] - m_new);
                const float p0 = __expf(v0 - m_new), p1 = __expf(v1 - m_new);
                const float p2 = __expf(v2 - m_new), p3 = __expf(v3 - m_new);
                float ps = p0 + p1 + p2 + p3;
#pragma unroll
                for (int sh = 1; sh < 16; sh <<= 1) ps += __shfl_xor(ps, sh, 64);
                l_run[qi][j] = l_run[qi][j] * corr + ps;
                m_run[qi][j] = m_new;
#pragma unroll
                for (int vf = 0; vf < 4; vf++) o_acc[qi][vf][j] *= corr;
                const int prow = w*32 + qi*16 + g*4 + j;
                Ps[prow][ 0 + r] = (bf16)p0;
                Ps[prow][16 + r] = (bf16)p1;
                Ps[prow][32 + r] = (bf16)p2;
                Ps[prow][48 + r] = (bf16)p3;
            }
        }
        // no barrier: each wave reads back only its own Ps rows (intra-wave dep)

        // ---- O += P * V ----
#pragma unroll
        for (int ks = 0; ks < 2; ks++) {
            bf16x8 pf[2], vfrag[4];
#pragma unroll
            for (int qi = 0; qi < 2; qi++)
                pf[qi] = *(const bf16x8*)&Ps[w*32 + qi*16 + r][ks*32 + g*8];
#pragma unroll
            for (int vf = 0; vf < 4; vf++)
                vfrag[vf] = *(const bf16x8*)&Vt[vf*16 + r][ks*32 + g*8];
#pragma unroll
            for (int qi = 0; qi < 2; qi++)
#pragma unroll
                for (int vf = 0; vf < 4; vf++)
                    o_acc[qi][vf] = __builtin_amdgcn_mfma_f32_16x16x32_bf16(
                        pf[qi], vfrag[vf], o_acc[qi][vf], 0, 0, 0);
        }
        __syncthreads();   // protect Ks/Vt before next stage
    }

    // ---- epilogue: normalize, store merged heads [B,S,512] bf16 ----
#pragma unroll
    for (int qi = 0; qi < 2; qi++) {
#pragma unroll
        for (int vf = 0; vf < 4; vf++) {
#pragma unroll
            for (int j = 0; j < 4; j++) {
                const int s = q0 + w*32 + qi*16 + g*4 + j;
                const int dcol = h*64 + vf*16 + r;
                const float val = o_acc[qi][vf][j] / l_run[qi][j];
                attn[((size_t)(b*2048) + s) * 512 + dcol] = (bf16)val;
            }
        }
    }
}

// ---------------------------------------------------------------------------
extern "C" void kernel_launch(void* const* d_in, const int* in_sizes, int n_in,
                              void* d_out, int out_size, void* d_ws, size_t ws_size,
                              hipStream_t stream)
{
    const float* q    = (const float*)d_in[0];
    const float* k    = (const float*)d_in[1];
    const float* v    = (const float*)d_in[2];
    const int*   mask = (const int*)  d_in[3];
    const float* wq   = (const float*)d_in[4];
    const float* bq   = (const float*)d_in[5];
    const float* wk   = (const float*)d_in[6];
    const float* bk   = (const float*)d_in[7];
    const float* wv   = (const float*)d_in[8];
    const float* bv   = (const float*)d_in[9];
    const float* wd   = (const float*)d_in[10];
    const float* bd   = (const float*)d_in[11];
    float* out = (float*)d_out;

    const size_t NELEM = (size_t)4 * 2048 * 512;   // 4,194,304
    bf16* qp = (bf16*)d_ws;
    bf16* kp = qp + NELEM;
    bf16* vp = kp + NELEM;
    bf16* ab = vp + NELEM;                          // merged attn output

    dim3 gg(64, 4), gb(256);
    gemm_kernel<0><<<gg, gb, 0, stream>>>((const void*)q, wq, bq, (void*)qp);
    gemm_kernel<0><<<gg, gb, 0, stream>>>((const void*)k, wk, bk, (void*)kp);
    gemm_kernel<0><<<gg, gb, 0, stream>>>((const void*)v, wv, bv, (void*)vp);

    attn_kernel<<<dim3(32, 16), dim3(256), 0, stream>>>(qp, kp, vp, mask, ab);

    gemm_kernel<1><<<gg, gb, 0, stream>>>((const void*)ab, wd, bd, (void*)out);
}

// Round 2
// 206.546 us; speedup vs baseline: 1.1253x; 1.1253x over previous
//
#include <hip/hip_runtime.h>
#include <hip/hip_bf16.h>
#include <cmath>

typedef __bf16 bf16;
typedef __attribute__((ext_vector_type(8))) __bf16 bf16x8;
typedef __attribute__((ext_vector_type(4))) __bf16 bf16x4;
typedef __attribute__((ext_vector_type(4))) float f32x4;

// ---------------------------------------------------------------------------
// prep_w: transpose + convert 4 weight matrices fp32 [512 k][512 n]
//         -> bf16 WT [512 n][512 k], one per blockIdx.z.
// ---------------------------------------------------------------------------
__global__ __launch_bounds__(256)
void prep_w(const float* __restrict__ w0, const float* __restrict__ w1,
            const float* __restrict__ w2, const float* __restrict__ w3,
            bf16* __restrict__ wt)
{
    const float* W = (blockIdx.z == 0) ? w0 : (blockIdx.z == 1) ? w1
                   : (blockIdx.z == 2) ? w2 : w3;
    bf16* WT = wt + (size_t)blockIdx.z * 512 * 512;

    __shared__ bf16 t[64][72];
    const int k0 = blockIdx.x * 64, n0 = blockIdx.y * 64;
    const int tid = threadIdx.x;
    {
        const int row = tid >> 2;            // k-local
        const int c0 = (tid & 3) * 16;       // n-local
        const float* src = W + (size_t)(k0 + row) * 512 + n0 + c0;
#pragma unroll
        for (int i = 0; i < 16; i += 4) {
            f32x4 f = *(const f32x4*)(src + i);
            t[c0 + i + 0][row] = (bf16)f[0];
            t[c0 + i + 1][row] = (bf16)f[1];
            t[c0 + i + 2][row] = (bf16)f[2];
            t[c0 + i + 3][row] = (bf16)f[3];
        }
    }
    __syncthreads();
    {
        const int nrow = tid >> 2;           // n-local
        const int c0 = (tid & 3) * 16;       // k-local
        bf16* dst = WT + (size_t)(n0 + nrow) * 512 + k0 + c0;
        *(bf16x8*)(dst)     = *(const bf16x8*)&t[nrow][c0];
        *(bf16x8*)(dst + 8) = *(const bf16x8*)&t[nrow][c0 + 8];
    }
}

// ---------------------------------------------------------------------------
// GEMM: C[M x 512] = A[M x 512] * W[512 x 512] + bias,  W given as WT bf16 [n][k]
// MODE 0: A fp32, output bf16 head-split [B,H,S,64]    (Q,K projections)
// MODE 1: A bf16, output fp32 flat [M,512]             (final projection)
// MODE 2: A fp32, output bf16 head-TRANSPOSED [B,H,64,S] (V projection)
// 128x128 tile, BK=32, 256 threads (4 waves, 2x2), 16x16x32 bf16 MFMA.
// ---------------------------------------------------------------------------
template<int MODE>
__global__ __launch_bounds__(256)
void gemm_kernel(const void* __restrict__ Ap, const bf16* __restrict__ WT,
                 const float* __restrict__ bias, void* __restrict__ Cp)
{
    const int K = 512;
    const int bm = blockIdx.x;           // M/128
    const int bn = blockIdx.y;           // 4
    const int tid = threadIdx.x;
    const int wave = tid >> 6, lane = tid & 63;
    const int wr = wave >> 1, wc = wave & 1;
    const int g = lane >> 4, r = lane & 15;

    __shared__ bf16 As[128][56];
    __shared__ bf16 Bs[128][56];         // Bs[n][k] = WT[col0+n][kt+k]

    f32x4 acc[4][4] = {};
    const int row0 = bm * 128;
    const int col0 = bn * 128;

    for (int kt = 0; kt < K; kt += 32) {
        // ---- stage A tile ----
        {
            const int arow = tid >> 1;
            const int k0 = (tid & 1) * 16;
            if (MODE != 1) {
                const float* A = (const float*)Ap;
                const float* src = A + (size_t)(row0 + arow) * K + kt + k0;
                f32x4 f0 = *(const f32x4*)(src);
                f32x4 f1 = *(const f32x4*)(src + 4);
                f32x4 f2 = *(const f32x4*)(src + 8);
                f32x4 f3 = *(const f32x4*)(src + 12);
                bf16x8 v0, v1;
#pragma unroll
                for (int i = 0; i < 4; i++) {
                    v0[i] = (bf16)f0[i]; v0[4+i] = (bf16)f1[i];
                    v1[i] = (bf16)f2[i]; v1[4+i] = (bf16)f3[i];
                }
                *(bf16x8*)&As[arow][k0]     = v0;
                *(bf16x8*)&As[arow][k0 + 8] = v1;
            } else {
                const bf16* A = (const bf16*)Ap;
                const bf16* src = A + (size_t)(row0 + arow) * K + kt + k0;
                *(bf16x8*)&As[arow][k0]     = *(const bf16x8*)(src);
                *(bf16x8*)&As[arow][k0 + 8] = *(const bf16x8*)(src + 8);
            }
        }
        // ---- stage B tile: straight bf16 copy from WT ----
        {
            const int n = tid >> 1;
            const int k0 = (tid & 1) * 16;
            const bf16* src = WT + (size_t)(col0 + n) * 512 + kt + k0;
            *(bf16x8*)&Bs[n][k0]     = *(const bf16x8*)(src);
            *(bf16x8*)&Bs[n][k0 + 8] = *(const bf16x8*)(src + 8);
        }
        __syncthreads();

        bf16x8 af[4], bfr[4];
#pragma unroll
        for (int mf = 0; mf < 4; mf++)
            af[mf] = *(const bf16x8*)&As[wr*64 + mf*16 + r][g*8];
#pragma unroll
        for (int nf = 0; nf < 4; nf++)
            bfr[nf] = *(const bf16x8*)&Bs[wc*64 + nf*16 + r][g*8];
#pragma unroll
        for (int mf = 0; mf < 4; mf++)
#pragma unroll
            for (int nf = 0; nf < 4; nf++)
                acc[mf][nf] = __builtin_amdgcn_mfma_f32_16x16x32_bf16(
                    af[mf], bfr[nf], acc[mf][nf], 0, 0, 0);
        __syncthreads();
    }

    // ---- epilogue ----
#pragma unroll
    for (int mf = 0; mf < 4; mf++) {
#pragma unroll
        for (int nf = 0; nf < 4; nf++) {
            const int rbase = row0 + wr*64 + mf*16 + g*4;
            const int ccol  = col0 + wc*64 + nf*16 + r;
            const float bi = bias[ccol];
            if (MODE == 0) {
                bf16* C = (bf16*)Cp;
#pragma unroll
                for (int j = 0; j < 4; j++) {
                    const int rrow = rbase + j;
                    const int b = rrow >> 11, s = rrow & 2047;
                    const int h = ccol >> 6, hd = ccol & 63;
                    C[(((size_t)(b*8 + h) * 2048) + s) * 64 + hd] =
                        (bf16)(acc[mf][nf][j] + bi);
                }
            } else if (MODE == 1) {
                float* C = (float*)Cp;
#pragma unroll
                for (int j = 0; j < 4; j++)
                    C[(size_t)(rbase + j) * 512 + ccol] = acc[mf][nf][j] + bi;
            } else {
                bf16* C = (bf16*)Cp;
                const int b = rbase >> 11, s = rbase & 2047;
                const int h = ccol >> 6, hd = ccol & 63;
                bf16x4 pk;
#pragma unroll
                for (int j = 0; j < 4; j++) pk[j] = (bf16)(acc[mf][nf][j] + bi);
                *(bf16x4*)(C + ((size_t)(b*8 + h) * 64 + hd) * 2048 + s) = pk;
            }
        }
    }
}

// ---------------------------------------------------------------------------
// Flash attention: block = one (b,h) x 64-query tile; 4 waves x 16 q-rows.
// qp/kp: bf16 [B,H,S,64]; vpT: bf16 [B,H,64,S]; out: bf16 [B,S,512] merged.
// LDS 27.9 KiB (Q/P union) -> 4 blocks/CU resident (grid 1024).
// ---------------------------------------------------------------------------
__global__ __launch_bounds__(256)
void attn_kernel(const bf16* __restrict__ qp, const bf16* __restrict__ kp,
                 const bf16* __restrict__ vpT, const int* __restrict__ mask,
                 bf16* __restrict__ attn)
{
    const int bh = blockIdx.x;           // 0..31
    const int qt = blockIdx.y;           // 0..31
    const int b = bh >> 3, h = bh & 7;
    const int tid = threadIdx.x;
    const int w = tid >> 6, lane = tid & 63;
    const int g = lane >> 4, r = lane & 15;

    __shared__ bf16 QPs[64][72];         // Q tile, then reused as P tile
    __shared__ bf16 Ks[64][72];          // [key][hd]
    __shared__ bf16 Vt[64][72];          // [hd][key] (direct from vpT)
    __shared__ float maskadd[64];

    const size_t head_base = (size_t)(b*8 + h) * 2048 * 64;
    const int q0 = qt * 64;

    // ---- load Q tile ----
    {
        const int row = tid >> 2;
        const int c0 = (tid & 3) * 16;
        const bf16* src = qp + head_base + (size_t)(q0 + row) * 64 + c0;
        *(bf16x8*)&QPs[row][c0]     = *(const bf16x8*)(src);
        *(bf16x8*)&QPs[row][c0 + 8] = *(const bf16x8*)(src + 8);
    }
    __syncthreads();

    bf16x8 qf[2];
#pragma unroll
    for (int ks = 0; ks < 2; ks++)
        qf[ks] = *(const bf16x8*)&QPs[w*16 + r][ks*32 + g*8];
    // all waves' qf reads complete before the first in-loop barrier, after
    // which P writes may overlay QPs.

    float m_run[4], l_run[4];
    f32x4 o_acc[4] = {};
#pragma unroll
    for (int j = 0; j < 4; j++) { m_run[j] = -INFINITY; l_run[j] = 0.f; }

    for (int kt = 0; kt < 2048; kt += 64) {
        {   // stage K tile [64 keys][64 hd]
            const int row = tid >> 2;
            const int c0 = (tid & 3) * 16;
            const bf16* src = kp + head_base + (size_t)(kt + row) * 64 + c0;
            *(bf16x8*)&Ks[row][c0]     = *(const bf16x8*)(src);
            *(bf16x8*)&Ks[row][c0 + 8] = *(const bf16x8*)(src + 8);
        }
        {   // stage V^T tile [64 hd][64 keys] -- straight copy, no transpose
            const int row = tid >> 2;
            const int c0 = (tid & 3) * 16;
            const bf16* src = vpT + head_base + (size_t)row * 2048 + kt + c0;
            *(bf16x8*)&Vt[row][c0]     = *(const bf16x8*)(src);
            *(bf16x8*)&Vt[row][c0 + 8] = *(const bf16x8*)(src + 8);
        }
        if (tid < 64) maskadd[tid] = -1e9f * (float)mask[b * 2048 + kt + tid];
        __syncthreads();

        // ---- scores = Q * K^T ----
        f32x4 sa[4] = {};
#pragma unroll
        for (int ks = 0; ks < 2; ks++) {
            bf16x8 kfrag[4];
#pragma unroll
            for (int kf = 0; kf < 4; kf++)
                kfrag[kf] = *(const bf16x8*)&Ks[kf*16 + r][ks*32 + g*8];
#pragma unroll
            for (int kf = 0; kf < 4; kf++)
                sa[kf] = __builtin_amdgcn_mfma_f32_16x16x32_bf16(
                    qf[ks], kfrag[kf], sa[kf], 0, 0, 0);
        }

        // ---- online softmax (C-layout rows: q = g*4+j, col = kf*16+r) ----
        float madd[4];
#pragma unroll
        for (int kf = 0; kf < 4; kf++) madd[kf] = maskadd[kf*16 + r];
#pragma unroll
        for (int j = 0; j < 4; j++) {
            float v0 = sa[0][j] * 0.125f + madd[0];
            float v1 = sa[1][j] * 0.125f + madd[1];
            float v2 = sa[2][j] * 0.125f + madd[2];
            float v3 = sa[3][j] * 0.125f + madd[3];
            float mx = fmaxf(fmaxf(v0, v1), fmaxf(v2, v3));
#pragma unroll
            for (int sh = 1; sh < 16; sh <<= 1) mx = fmaxf(mx, __shfl_xor(mx, sh, 64));
            const float m_new = fmaxf(m_run[j], mx);
            const float corr = __expf(m_run[j] - m_new);
            const float p0 = __expf(v0 - m_new), p1 = __expf(v1 - m_new);
            const float p2 = __expf(v2 - m_new), p3 = __expf(v3 - m_new);
            float ps = p0 + p1 + p2 + p3;
#pragma unroll
            for (int sh = 1; sh < 16; sh <<= 1) ps += __shfl_xor(ps, sh, 64);
            l_run[j] = l_run[j] * corr + ps;
            m_run[j] = m_new;
#pragma unroll
            for (int vf = 0; vf < 4; vf++) o_acc[vf][j] *= corr;
            const int prow = w*16 + g*4 + j;
            QPs[prow][ 0 + r] = (bf16)p0;
            QPs[prow][16 + r] = (bf16)p1;
            QPs[prow][32 + r] = (bf16)p2;
            QPs[prow][48 + r] = (bf16)p3;
        }
        // intra-wave dependency only: each wave reads back its own P rows

        // ---- O += P * V ----
#pragma unroll
        for (int ks = 0; ks < 2; ks++) {
            bf16x8 pf = *(const bf16x8*)&QPs[w*16 + r][ks*32 + g*8];
            bf16x8 vfrag[4];
#pragma unroll
            for (int vf = 0; vf < 4; vf++)
                vfrag[vf] = *(const bf16x8*)&Vt[vf*16 + r][ks*32 + g*8];
#pragma unroll
            for (int vf = 0; vf < 4; vf++)
                o_acc[vf] = __builtin_amdgcn_mfma_f32_16x16x32_bf16(
                    pf, vfrag[vf], o_acc[vf], 0, 0, 0);
        }
        __syncthreads();   // protect Ks/Vt/QPs before next stage
    }

    // ---- epilogue: normalize, store merged heads [B,S,512] bf16 ----
#pragma unroll
    for (int vf = 0; vf < 4; vf++) {
#pragma unroll
        for (int j = 0; j < 4; j++) {
            const int s = q0 + w*16 + g*4 + j;
            const int dcol = h*64 + vf*16 + r;
            attn[((size_t)(b*2048) + s) * 512 + dcol] =
                (bf16)(o_acc[vf][j] / l_run[j]);
        }
    }
}

// ---------------------------------------------------------------------------
extern "C" void kernel_launch(void* const* d_in, const int* in_sizes, int n_in,
                              void* d_out, int out_size, void* d_ws, size_t ws_size,
                              hipStream_t stream)
{
    const float* q    = (const float*)d_in[0];
    const float* k    = (const float*)d_in[1];
    const float* v    = (const float*)d_in[2];
    const int*   mask = (const int*)  d_in[3];
    const float* wq   = (const float*)d_in[4];
    const float* bq   = (const float*)d_in[5];
    const float* wk   = (const float*)d_in[6];
    const float* bk   = (const float*)d_in[7];
    const float* wv   = (const float*)d_in[8];
    const float* bv   = (const float*)d_in[9];
    const float* wd   = (const float*)d_in[10];
    const float* bd   = (const float*)d_in[11];
    float* out = (float*)d_out;

    const size_t NELEM = (size_t)4 * 2048 * 512;   // 4,194,304
    bf16* qp  = (bf16*)d_ws;
    bf16* kp  = qp + NELEM;
    bf16* vpT = kp + NELEM;                         // [B,H,64,S]
    bf16* ab  = vpT + NELEM;                        // merged attn output
    bf16* wt  = ab + NELEM;                         // 4 x 512x512 bf16

    prep_w<<<dim3(8, 8, 4), dim3(256), 0, stream>>>(wq, wk, wv, wd, wt);

    dim3 gg(64, 4), gb(256);
    gemm_kernel<0><<<gg, gb, 0, stream>>>((const void*)q, wt + 0*262144, bq, (void*)qp);
    gemm_kernel<0><<<gg, gb, 0, stream>>>((const void*)k, wt + 1*262144, bk, (void*)kp);
    gemm_kernel<2><<<gg, gb, 0, stream>>>((const void*)v, wt + 2*262144, bv, (void*)vpT);

    attn_kernel<<<dim3(32, 32), dim3(256), 0, stream>>>(qp, kp, vpT, mask, ab);

    gemm_kernel<1><<<gg, gb, 0, stream>>>((const void*)ab, wt + 3*262144, bd, (void*)out);
}

// Round 3
// 161.975 us; speedup vs baseline: 1.4349x; 1.2752x over previous
//
#include <hip/hip_runtime.h>
#include <hip/hip_bf16.h>
#include <cmath>

typedef __bf16 bf16;
typedef __attribute__((ext_vector_type(8))) __bf16 bf16x8;
typedef __attribute__((ext_vector_type(4))) __bf16 bf16x4;
typedef __attribute__((ext_vector_type(4))) float f32x4;

// ---------------------------------------------------------------------------
// prep_w: transpose + convert 4 weight matrices fp32 [512 k][512 n]
//         -> bf16 WT [512 n][512 k], one per blockIdx.z.
// ---------------------------------------------------------------------------
__global__ __launch_bounds__(256)
void prep_w(const float* __restrict__ w0, const float* __restrict__ w1,
            const float* __restrict__ w2, const float* __restrict__ w3,
            bf16* __restrict__ wt)
{
    const float* W = (blockIdx.z == 0) ? w0 : (blockIdx.z == 1) ? w1
                   : (blockIdx.z == 2) ? w2 : w3;
    bf16* WT = wt + (size_t)blockIdx.z * 512 * 512;

    __shared__ bf16 t[64][72];
    const int k0 = blockIdx.x * 64, n0 = blockIdx.y * 64;
    const int tid = threadIdx.x;
    {
        const int row = tid >> 2;            // k-local
        const int c0 = (tid & 3) * 16;       // n-local
        const float* src = W + (size_t)(k0 + row) * 512 + n0 + c0;
#pragma unroll
        for (int i = 0; i < 16; i += 4) {
            f32x4 f = *(const f32x4*)(src + i);
            t[c0 + i + 0][row] = (bf16)f[0];
            t[c0 + i + 1][row] = (bf16)f[1];
            t[c0 + i + 2][row] = (bf16)f[2];
            t[c0 + i + 3][row] = (bf16)f[3];
        }
    }
    __syncthreads();
    {
        const int nrow = tid >> 2;           // n-local
        const int c0 = (tid & 3) * 16;       // k-local
        bf16* dst = WT + (size_t)(n0 + nrow) * 512 + k0 + c0;
        *(bf16x8*)(dst)     = *(const bf16x8*)&t[nrow][c0];
        *(bf16x8*)(dst + 8) = *(const bf16x8*)&t[nrow][c0 + 8];
    }
}

// ---------------------------------------------------------------------------
// GEMM: C[M x 512] = A[M x 512] * W[512 x 512] + bias,  W given as WT bf16 [n][k]
// MODE 0: A fp32, output bf16 head-split [B,H,S,64]    (Q,K projections)
// MODE 1: A bf16, output fp32 flat [M,512]             (final projection)
// MODE 2: A fp32, output bf16 head-TRANSPOSED [B,H,64,S] (V projection)
// ---------------------------------------------------------------------------
template<int MODE>
__global__ __launch_bounds__(256)
void gemm_kernel(const void* __restrict__ Ap, const bf16* __restrict__ WT,
                 const float* __restrict__ bias, void* __restrict__ Cp)
{
    const int K = 512;
    const int bm = blockIdx.x;
    const int bn = blockIdx.y;
    const int tid = threadIdx.x;
    const int wave = tid >> 6, lane = tid & 63;
    const int wr = wave >> 1, wc = wave & 1;
    const int g = lane >> 4, r = lane & 15;

    __shared__ bf16 As[128][56];
    __shared__ bf16 Bs[128][56];

    f32x4 acc[4][4] = {};
    const int row0 = bm * 128;
    const int col0 = bn * 128;

    for (int kt = 0; kt < K; kt += 32) {
        {
            const int arow = tid >> 1;
            const int k0 = (tid & 1) * 16;
            if (MODE != 1) {
                const float* A = (const float*)Ap;
                const float* src = A + (size_t)(row0 + arow) * K + kt + k0;
                f32x4 f0 = *(const f32x4*)(src);
                f32x4 f1 = *(const f32x4*)(src + 4);
                f32x4 f2 = *(const f32x4*)(src + 8);
                f32x4 f3 = *(const f32x4*)(src + 12);
                bf16x8 v0, v1;
#pragma unroll
                for (int i = 0; i < 4; i++) {
                    v0[i] = (bf16)f0[i]; v0[4+i] = (bf16)f1[i];
                    v1[i] = (bf16)f2[i]; v1[4+i] = (bf16)f3[i];
                }
                *(bf16x8*)&As[arow][k0]     = v0;
                *(bf16x8*)&As[arow][k0 + 8] = v1;
            } else {
                const bf16* A = (const bf16*)Ap;
                const bf16* src = A + (size_t)(row0 + arow) * K + kt + k0;
                *(bf16x8*)&As[arow][k0]     = *(const bf16x8*)(src);
                *(bf16x8*)&As[arow][k0 + 8] = *(const bf16x8*)(src + 8);
            }
        }
        {
            const int n = tid >> 1;
            const int k0 = (tid & 1) * 16;
            const bf16* src = WT + (size_t)(col0 + n) * 512 + kt + k0;
            *(bf16x8*)&Bs[n][k0]     = *(const bf16x8*)(src);
            *(bf16x8*)&Bs[n][k0 + 8] = *(const bf16x8*)(src + 8);
        }
        __syncthreads();

        bf16x8 af[4], bfr[4];
#pragma unroll
        for (int mf = 0; mf < 4; mf++)
            af[mf] = *(const bf16x8*)&As[wr*64 + mf*16 + r][g*8];
#pragma unroll
        for (int nf = 0; nf < 4; nf++)
            bfr[nf] = *(const bf16x8*)&Bs[wc*64 + nf*16 + r][g*8];
#pragma unroll
        for (int mf = 0; mf < 4; mf++)
#pragma unroll
            for (int nf = 0; nf < 4; nf++)
                acc[mf][nf] = __builtin_amdgcn_mfma_f32_16x16x32_bf16(
                    af[mf], bfr[nf], acc[mf][nf], 0, 0, 0);
        __syncthreads();
    }

#pragma unroll
    for (int mf = 0; mf < 4; mf++) {
#pragma unroll
        for (int nf = 0; nf < 4; nf++) {
            const int rbase = row0 + wr*64 + mf*16 + g*4;
            const int ccol  = col0 + wc*64 + nf*16 + r;
            const float bi = bias[ccol];
            if (MODE == 0) {
                bf16* C = (bf16*)Cp;
#pragma unroll
                for (int j = 0; j < 4; j++) {
                    const int rrow = rbase + j;
                    const int b = rrow >> 11, s = rrow & 2047;
                    const int h = ccol >> 6, hd = ccol & 63;
                    C[(((size_t)(b*8 + h) * 2048) + s) * 64 + hd] =
                        (bf16)(acc[mf][nf][j] + bi);
                }
            } else if (MODE == 1) {
                float* C = (float*)Cp;
#pragma unroll
                for (int j = 0; j < 4; j++)
                    C[(size_t)(rbase + j) * 512 + ccol] = acc[mf][nf][j] + bi;
            } else {
                bf16* C = (bf16*)Cp;
                const int b = rbase >> 11, s = rbase & 2047;
                const int h = ccol >> 6, hd = ccol & 63;
                bf16x4 pk;
#pragma unroll
                for (int j = 0; j < 4; j++) pk[j] = (bf16)(acc[mf][nf][j] + bi);
                *(bf16x4*)(C + ((size_t)(b*8 + h) * 64 + hd) * 2048 + s) = pk;
            }
        }
    }
}

// ---------------------------------------------------------------------------
// Flash attention, swapped-operand form.
// S^T = mfma(K,Q): each lane owns ONE query (q = w*16 + (lane&15)); scores for
// 16 keys live in registers -> softmax is register-local + 2 shuffles.
// O^T = mfma(V^T, P^T): corr/l are per-lane scalars, no cross-lane gather.
// K/V prefetched to registers one tile ahead (T14). Defer-max (T13, THR=8).
// ---------------------------------------------------------------------------
__global__ __launch_bounds__(256)
void attn_kernel(const bf16* __restrict__ qp, const bf16* __restrict__ kp,
                 const bf16* __restrict__ vpT, const int* __restrict__ mask,
                 bf16* __restrict__ attn)
{
    const int bh = blockIdx.x;           // 0..31
    const int qt = blockIdx.y;           // 0..31
    const int b = bh >> 3, h = bh & 7;
    const int tid = threadIdx.x;
    const int w = tid >> 6, lane = tid & 63;
    const int g = (lane >> 4) & 3, r = lane & 15;

    __shared__ bf16 QPs[64][72];                 // Q tile, then reused as P
    __shared__ bf16 Ks[64][72];                  // [key][hd]
    __shared__ bf16 Vt[64][72];                  // [hd][key]
    __shared__ __align__(16) float maskadd[64];

    const size_t head_base = (size_t)(b*8 + h) * 2048 * 64;
    const int q0 = qt * 64;
    const bf16* kbase = kp  + head_base;
    const bf16* vbase = vpT + head_base;

    // ---- load Q tile ----
    {
        const int row = tid >> 2;
        const int c0 = (tid & 3) * 16;
        const bf16* src = qp + head_base + (size_t)(q0 + row) * 64 + c0;
        *(bf16x8*)&QPs[row][c0]     = *(const bf16x8*)(src);
        *(bf16x8*)&QPs[row][c0 + 8] = *(const bf16x8*)(src + 8);
    }
    __syncthreads();

    bf16x8 qf[2];
#pragma unroll
    for (int ks = 0; ks < 2; ks++)
        qf[ks] = *(const bf16x8*)&QPs[w*16 + r][ks*32 + g*8];
    // qf reads complete before the first in-loop barrier; P may overlay after.

    float m_run = -INFINITY, l_run = 0.f;
    f32x4 o_accT[4] = {};                        // O^T: d = vf*16+g*4+j, q = w*16+r

    // ---- register prefetch state (T14) ----
    const int srow = tid >> 2;                   // staging row 0..63
    const int sc0  = (tid & 3) * 16;
    bf16x8 kr0{}, kr1{}, vr0{}, vr1{};
    int mreg = 0;
    {
        const bf16* ksrc = kbase + (size_t)srow * 64 + sc0;
        kr0 = *(const bf16x8*)(ksrc); kr1 = *(const bf16x8*)(ksrc + 8);
        const bf16* vsrc = vbase + (size_t)srow * 2048 + sc0;
        vr0 = *(const bf16x8*)(vsrc); vr1 = *(const bf16x8*)(vsrc + 8);
        if (tid < 64) mreg = mask[b * 2048 + tid];
    }

    for (int kt = 0; kt < 2048; kt += 64) {
        // ---- write staged tile to LDS ----
        *(bf16x8*)&Ks[srow][sc0]     = kr0;
        *(bf16x8*)&Ks[srow][sc0 + 8] = kr1;
        *(bf16x8*)&Vt[srow][sc0]     = vr0;
        *(bf16x8*)&Vt[srow][sc0 + 8] = vr1;
        if (tid < 64) maskadd[tid] = -1e9f * (float)mreg;
        __syncthreads();

        // ---- prefetch next tile into registers (hides under compute) ----
        if (kt + 64 < 2048) {
            const bf16* ksrc = kbase + (size_t)(kt + 64 + srow) * 64 + sc0;
            kr0 = *(const bf16x8*)(ksrc); kr1 = *(const bf16x8*)(ksrc + 8);
            const bf16* vsrc = vbase + (size_t)srow * 2048 + kt + 64 + sc0;
            vr0 = *(const bf16x8*)(vsrc); vr1 = *(const bf16x8*)(vsrc + 8);
            if (tid < 64) mreg = mask[b * 2048 + kt + 64 + tid];
        }

        // ---- S^T = K * Q^T : sa[kf][j] = score(key kf*16+g*4+j, q=w*16+r) ----
        f32x4 sa[4] = {};
        __builtin_amdgcn_s_setprio(1);
#pragma unroll
        for (int ks = 0; ks < 2; ks++) {
            bf16x8 kfrag[4];
#pragma unroll
            for (int kf = 0; kf < 4; kf++)
                kfrag[kf] = *(const bf16x8*)&Ks[kf*16 + r][ks*32 + g*8];
#pragma unroll
            for (int kf = 0; kf < 4; kf++)
                sa[kf] = __builtin_amdgcn_mfma_f32_16x16x32_bf16(
                    kfrag[kf], qf[ks], sa[kf], 0, 0, 0);
        }
        __builtin_amdgcn_s_setprio(0);

        // ---- per-lane softmax over 16 local scores + 2-shuffle reduce ----
        f32x4 sv[4];
        float mx = -INFINITY;
#pragma unroll
        for (int kf = 0; kf < 4; kf++) {
            const f32x4 ma = *(const f32x4*)&maskadd[kf*16 + g*4];
            sv[kf] = sa[kf] * 0.125f + ma;
#pragma unroll
            for (int j = 0; j < 4; j++) mx = fmaxf(mx, sv[kf][j]);
        }
        mx = fmaxf(mx, __shfl_xor(mx, 16, 64));
        mx = fmaxf(mx, __shfl_xor(mx, 32, 64));

        if (!__all(mx <= m_run + 8.f)) {         // defer-max: skip tiny growth
            const float m_new = fmaxf(m_run, mx);
            const float corr = __expf(m_run - m_new);
#pragma unroll
            for (int vf = 0; vf < 4; vf++) o_accT[vf] *= corr;
            l_run *= corr;
            m_run = m_new;
        }

        float psum = 0.f;
        bf16x4 pk[4];
#pragma unroll
        for (int kf = 0; kf < 4; kf++) {
#pragma unroll
            for (int j = 0; j < 4; j++) {
                const float p = __expf(sv[kf][j] - m_run);
                psum += p;
                pk[kf][j] = (bf16)p;
            }
        }
        psum += __shfl_xor(psum, 16, 64);
        psum += __shfl_xor(psum, 32, 64);
        l_run += psum;

        // ---- store P rows (conflict-free b64, intra-wave rows) ----
#pragma unroll
        for (int kf = 0; kf < 4; kf++)
            *(bf16x4*)&QPs[w*16 + r][kf*16 + g*4] = pk[kf];

        // ---- O^T += V^T * P^T ----
        __builtin_amdgcn_s_setprio(1);
#pragma unroll
        for (int ks = 0; ks < 2; ks++) {
            const bf16x8 pf = *(const bf16x8*)&QPs[w*16 + r][ks*32 + g*8];
            bf16x8 vfrag[4];
#pragma unroll
            for (int vf = 0; vf < 4; vf++)
                vfrag[vf] = *(const bf16x8*)&Vt[vf*16 + r][ks*32 + g*8];
#pragma unroll
            for (int vf = 0; vf < 4; vf++)
                o_accT[vf] = __builtin_amdgcn_mfma_f32_16x16x32_bf16(
                    vfrag[vf], pf, o_accT[vf], 0, 0, 0);
        }
        __builtin_amdgcn_s_setprio(0);
        __syncthreads();                         // protect Ks/Vt/QPs
    }

    // ---- epilogue: O^T is lane-local per query; normalize & store ----
    const float inv = 1.0f / l_run;
    const int s = q0 + w*16 + r;
    bf16* dst = attn + ((size_t)(b*2048) + s) * 512 + h*64 + g*4;
#pragma unroll
    for (int vf = 0; vf < 4; vf++) {
        bf16x4 ov;
#pragma unroll
        for (int j = 0; j < 4; j++) ov[j] = (bf16)(o_accT[vf][j] * inv);
        *(bf16x4*)(dst + vf*16) = ov;
    }
}

// ---------------------------------------------------------------------------
extern "C" void kernel_launch(void* const* d_in, const int* in_sizes, int n_in,
                              void* d_out, int out_size, void* d_ws, size_t ws_size,
                              hipStream_t stream)
{
    const float* q    = (const float*)d_in[0];
    const float* k    = (const float*)d_in[1];
    const float* v    = (const float*)d_in[2];
    const int*   mask = (const int*)  d_in[3];
    const float* wq   = (const float*)d_in[4];
    const float* bq   = (const float*)d_in[5];
    const float* wk   = (const float*)d_in[6];
    const float* bk   = (const float*)d_in[7];
    const float* wv   = (const float*)d_in[8];
    const float* bv   = (const float*)d_in[9];
    const float* wd   = (const float*)d_in[10];
    const float* bd   = (const float*)d_in[11];
    float* out = (float*)d_out;

    const size_t NELEM = (size_t)4 * 2048 * 512;   // 4,194,304
    bf16* qp  = (bf16*)d_ws;
    bf16* kp  = qp + NELEM;
    bf16* vpT = kp + NELEM;                         // [B,H,64,S]
    bf16* ab  = vpT + NELEM;                        // merged attn output
    bf16* wt  = ab + NELEM;                         // 4 x 512x512 bf16

    prep_w<<<dim3(8, 8, 4), dim3(256), 0, stream>>>(wq, wk, wv, wd, wt);

    dim3 gg(64, 4), gb(256);
    gemm_kernel<0><<<gg, gb, 0, stream>>>((const void*)q, wt + 0*262144, bq, (void*)qp);
    gemm_kernel<0><<<gg, gb, 0, stream>>>((const void*)k, wt + 1*262144, bk, (void*)kp);
    gemm_kernel<2><<<gg, gb, 0, stream>>>((const void*)v, wt + 2*262144, bv, (void*)vpT);

    attn_kernel<<<dim3(32, 32), dim3(256), 0, stream>>>(qp, kp, vpT, mask, ab);

    gemm_kernel<1><<<gg, gb, 0, stream>>>((const void*)ab, wt + 3*262144, bd, (void*)out);
}

// Round 4
// 148.394 us; speedup vs baseline: 1.5663x; 1.0915x over previous
//
#include <hip/hip_runtime.h>
#include <hip/hip_bf16.h>
#include <cmath>

typedef __bf16 bf16;
typedef __attribute__((ext_vector_type(8))) __bf16 bf16x8;
typedef __attribute__((ext_vector_type(4))) __bf16 bf16x4;
typedef __attribute__((ext_vector_type(4))) float f32x4;

#define LOG2E 1.4426950408889634f

// ---------------------------------------------------------------------------
// prep_w: transpose + convert 4 weight matrices fp32 [512 k][512 n]
//         -> bf16 WT [512 n][512 k], one per blockIdx.z.
// ---------------------------------------------------------------------------
__global__ __launch_bounds__(256)
void prep_w(const float* __restrict__ w0, const float* __restrict__ w1,
            const float* __restrict__ w2, const float* __restrict__ w3,
            bf16* __restrict__ wt)
{
    const float* W = (blockIdx.z == 0) ? w0 : (blockIdx.z == 1) ? w1
                   : (blockIdx.z == 2) ? w2 : w3;
    bf16* WT = wt + (size_t)blockIdx.z * 512 * 512;

    __shared__ bf16 t[64][72];
    const int k0 = blockIdx.x * 64, n0 = blockIdx.y * 64;
    const int tid = threadIdx.x;
    {
        const int row = tid >> 2;            // k-local
        const int c0 = (tid & 3) * 16;       // n-local
        const float* src = W + (size_t)(k0 + row) * 512 + n0 + c0;
#pragma unroll
        for (int i = 0; i < 16; i += 4) {
            f32x4 f = *(const f32x4*)(src + i);
            t[c0 + i + 0][row] = (bf16)f[0];
            t[c0 + i + 1][row] = (bf16)f[1];
            t[c0 + i + 2][row] = (bf16)f[2];
            t[c0 + i + 3][row] = (bf16)f[3];
        }
    }
    __syncthreads();
    {
        const int nrow = tid >> 2;           // n-local
        const int c0 = (tid & 3) * 16;       // k-local
        bf16* dst = WT + (size_t)(n0 + nrow) * 512 + k0 + c0;
        *(bf16x8*)(dst)     = *(const bf16x8*)&t[nrow][c0];
        *(bf16x8*)(dst + 8) = *(const bf16x8*)&t[nrow][c0 + 8];
    }
}

// ---------------------------------------------------------------------------
// GEMM: C[M x 512] = (A[M x 512] * W + bias) * scale,  W given as WT bf16 [n][k]
// MODE 0: A fp32, output bf16 head-split [B,H,S,64]    (Q,K projections)
// MODE 1: A bf16, output fp32 flat [M,512]             (final projection)
// MODE 2: A fp32, output bf16 head-TRANSPOSED [B,H,64,S] (V projection)
// ---------------------------------------------------------------------------
template<int MODE>
__global__ __launch_bounds__(256)
void gemm_kernel(const void* __restrict__ Ap, const bf16* __restrict__ WT,
                 const float* __restrict__ bias, void* __restrict__ Cp,
                 float scale)
{
    const int K = 512;
    const int bm = blockIdx.x;
    const int bn = blockIdx.y;
    const int tid = threadIdx.x;
    const int wave = tid >> 6, lane = tid & 63;
    const int wr = wave >> 1, wc = wave & 1;
    const int g = lane >> 4, r = lane & 15;

    __shared__ bf16 As[128][56];
    __shared__ bf16 Bs[128][56];

    f32x4 acc[4][4] = {};
    const int row0 = bm * 128;
    const int col0 = bn * 128;

    for (int kt = 0; kt < K; kt += 32) {
        {
            const int arow = tid >> 1;
            const int k0 = (tid & 1) * 16;
            if (MODE != 1) {
                const float* A = (const float*)Ap;
                const float* src = A + (size_t)(row0 + arow) * K + kt + k0;
                f32x4 f0 = *(const f32x4*)(src);
                f32x4 f1 = *(const f32x4*)(src + 4);
                f32x4 f2 = *(const f32x4*)(src + 8);
                f32x4 f3 = *(const f32x4*)(src + 12);
                bf16x8 v0, v1;
#pragma unroll
                for (int i = 0; i < 4; i++) {
                    v0[i] = (bf16)f0[i]; v0[4+i] = (bf16)f1[i];
                    v1[i] = (bf16)f2[i]; v1[4+i] = (bf16)f3[i];
                }
                *(bf16x8*)&As[arow][k0]     = v0;
                *(bf16x8*)&As[arow][k0 + 8] = v1;
            } else {
                const bf16* A = (const bf16*)Ap;
                const bf16* src = A + (size_t)(row0 + arow) * K + kt + k0;
                *(bf16x8*)&As[arow][k0]     = *(const bf16x8*)(src);
                *(bf16x8*)&As[arow][k0 + 8] = *(const bf16x8*)(src + 8);
            }
        }
        {
            const int n = tid >> 1;
            const int k0 = (tid & 1) * 16;
            const bf16* src = WT + (size_t)(col0 + n) * 512 + kt + k0;
            *(bf16x8*)&Bs[n][k0]     = *(const bf16x8*)(src);
            *(bf16x8*)&Bs[n][k0 + 8] = *(const bf16x8*)(src + 8);
        }
        __syncthreads();

        bf16x8 af[4], bfr[4];
#pragma unroll
        for (int mf = 0; mf < 4; mf++)
            af[mf] = *(const bf16x8*)&As[wr*64 + mf*16 + r][g*8];
#pragma unroll
        for (int nf = 0; nf < 4; nf++)
            bfr[nf] = *(const bf16x8*)&Bs[wc*64 + nf*16 + r][g*8];
#pragma unroll
        for (int mf = 0; mf < 4; mf++)
#pragma unroll
            for (int nf = 0; nf < 4; nf++)
                acc[mf][nf] = __builtin_amdgcn_mfma_f32_16x16x32_bf16(
                    af[mf], bfr[nf], acc[mf][nf], 0, 0, 0);
        __syncthreads();
    }

#pragma unroll
    for (int mf = 0; mf < 4; mf++) {
#pragma unroll
        for (int nf = 0; nf < 4; nf++) {
            const int rbase = row0 + wr*64 + mf*16 + g*4;
            const int ccol  = col0 + wc*64 + nf*16 + r;
            const float bi = bias[ccol];
            if (MODE == 0) {
                bf16* C = (bf16*)Cp;
#pragma unroll
                for (int j = 0; j < 4; j++) {
                    const int rrow = rbase + j;
                    const int b = rrow >> 11, s = rrow & 2047;
                    const int h = ccol >> 6, hd = ccol & 63;
                    C[(((size_t)(b*8 + h) * 2048) + s) * 64 + hd] =
                        (bf16)((acc[mf][nf][j] + bi) * scale);
                }
            } else if (MODE == 1) {
                float* C = (float*)Cp;
#pragma unroll
                for (int j = 0; j < 4; j++)
                    C[(size_t)(rbase + j) * 512 + ccol] = acc[mf][nf][j] + bi;
            } else {
                bf16* C = (bf16*)Cp;
                const int b = rbase >> 11, s = rbase & 2047;
                const int h = ccol >> 6, hd = ccol & 63;
                bf16x4 pk;
#pragma unroll
                for (int j = 0; j < 4; j++) pk[j] = (bf16)(acc[mf][nf][j] + bi);
                *(bf16x4*)(C + ((size_t)(b*8 + h) * 64 + hd) * 2048 + s) = pk;
            }
        }
    }
}

// ---------------------------------------------------------------------------
// Flash attention, swapped-operand, 2 q-subtiles per wave (32 q/wave).
// Block = (b,h) x 128 queries, 4 waves. K/V double-buffered in LDS, one
// barrier per tile. Softmax in exp2 domain (Q pre-scaled by 0.125*log2e).
// l accumulated via ones-MFMA row. Defer-max THR = 8 nats = 11.54 bits.
// ---------------------------------------------------------------------------
__global__ __launch_bounds__(256)
void attn_kernel(const bf16* __restrict__ qp, const bf16* __restrict__ kp,
                 const bf16* __restrict__ vpT, const int* __restrict__ mask,
                 bf16* __restrict__ attn)
{
    const int bh = blockIdx.x;           // 0..31
    const int qt = blockIdx.y;           // 0..15
    const int b = bh >> 3, h = bh & 7;
    const int tid = threadIdx.x;
    const int w = tid >> 6, lane = tid & 63;
    const int g = (lane >> 4) & 3, r = lane & 15;

    __shared__ bf16 QPs[128][72];                // Q tile, then reused as P
    __shared__ bf16 Ks[2][64][72];               // [buf][key][hd]
    __shared__ bf16 Vt[2][64][72];               // [buf][hd][key]
    __shared__ __align__(16) float madd2[2048];  // mask * -1e9*log2e

    const size_t head_base = (size_t)(b*8 + h) * 2048 * 64;
    const int q0 = qt * 128;
    const bf16* kbase = kp  + head_base;
    const bf16* vbase = vpT + head_base;

    // ---- stage mask additive (whole row, once) ----
    {
        const int4* m4 = (const int4*)(mask + b * 2048);
#pragma unroll
        for (int i = 0; i < 2; i++) {
            const int4 mv = m4[tid*2 + i];
            f32x4 f;
            f[0] = mv.x ? -1.4426950e9f : 0.f;
            f[1] = mv.y ? -1.4426950e9f : 0.f;
            f[2] = mv.z ? -1.4426950e9f : 0.f;
            f[3] = mv.w ? -1.4426950e9f : 0.f;
            *(f32x4*)&madd2[tid*8 + i*4] = f;
        }
    }
    // ---- load Q tile (wave w writes exactly rows [32w,32w+32) it reads) ----
    {
        const int row = tid >> 1;
        const int c0 = (tid & 1) * 32;
        const bf16* src = qp + head_base + (size_t)(q0 + row) * 64 + c0;
        *(bf16x8*)&QPs[row][c0]      = *(const bf16x8*)(src);
        *(bf16x8*)&QPs[row][c0 +  8] = *(const bf16x8*)(src + 8);
        *(bf16x8*)&QPs[row][c0 + 16] = *(const bf16x8*)(src + 16);
        *(bf16x8*)&QPs[row][c0 + 24] = *(const bf16x8*)(src + 24);
    }
    bf16x8 qf[2][2];
#pragma unroll
    for (int qs = 0; qs < 2; qs++)
#pragma unroll
        for (int ks = 0; ks < 2; ks++)
            qf[qs][ks] = *(const bf16x8*)&QPs[w*32 + qs*16 + r][ks*32 + g*8];

    // ---- staging lane mapping + preload tile 0 into buf 0 ----
    const int srow = tid >> 2;
    const int sc0  = (tid & 3) * 16;
    bf16x8 kr0, kr1, vr0, vr1;
    kr0 = *(const bf16x8*)(kbase + (size_t)srow * 64 + sc0);
    kr1 = *(const bf16x8*)(kbase + (size_t)srow * 64 + sc0 + 8);
    vr0 = *(const bf16x8*)(vbase + (size_t)srow * 2048 + sc0);
    vr1 = *(const bf16x8*)(vbase + (size_t)srow * 2048 + sc0 + 8);
    *(bf16x8*)&Ks[0][srow][sc0]     = kr0;
    *(bf16x8*)&Ks[0][srow][sc0 + 8] = kr1;
    *(bf16x8*)&Vt[0][srow][sc0]     = vr0;
    *(bf16x8*)&Vt[0][srow][sc0 + 8] = vr1;

    float m2[2] = {-INFINITY, -INFINITY};
    f32x4 oT[2][4] = {};                         // O^T per qsub
    f32x4 lac[2] = {};                           // l via ones-MFMA row
    bf16x8 ones;
#pragma unroll
    for (int i = 0; i < 8; i++) ones[i] = (bf16)1.0f;

    int it = 0;
    for (int kt = 0; kt < 2048; kt += 64, it ^= 1) {
        __syncthreads();                         // buf[it] ready for all
        const bool more = (kt + 64) < 2048;
        if (more) {                              // prefetch next tile to regs
            kr0 = *(const bf16x8*)(kbase + (size_t)(kt+64+srow)*64 + sc0);
            kr1 = *(const bf16x8*)(kbase + (size_t)(kt+64+srow)*64 + sc0 + 8);
            vr0 = *(const bf16x8*)(vbase + (size_t)srow*2048 + kt+64 + sc0);
            vr1 = *(const bf16x8*)(vbase + (size_t)srow*2048 + kt+64 + sc0 + 8);
        }

        // ---- S^T = K*Q^T : sa[qs][kf][j] = score(key kf*16+g*4+j, q 32w+16qs+r)
        f32x4 sa[2][4] = {};
        __builtin_amdgcn_s_setprio(1);
#pragma unroll
        for (int ks = 0; ks < 2; ks++) {
            bf16x8 kfrag[4];
#pragma unroll
            for (int kf = 0; kf < 4; kf++)
                kfrag[kf] = *(const bf16x8*)&Ks[it][kf*16 + r][ks*32 + g*8];
#pragma unroll
            for (int qs = 0; qs < 2; qs++)
#pragma unroll
                for (int kf = 0; kf < 4; kf++)
                    sa[qs][kf] = __builtin_amdgcn_mfma_f32_16x16x32_bf16(
                        kfrag[kf], qf[qs][ks], sa[qs][kf], 0, 0, 0);
        }
        __builtin_amdgcn_s_setprio(0);

        f32x4 ma[4];
#pragma unroll
        for (int kf = 0; kf < 4; kf++)
            ma[kf] = *(const f32x4*)&madd2[kt + kf*16 + g*4];

        // ---- per-lane softmax (exp2 domain), P -> LDS ----
#pragma unroll
        for (int qs = 0; qs < 2; qs++) {
            f32x4 sv[4];
            float mx = -INFINITY;
#pragma unroll
            for (int kf = 0; kf < 4; kf++) {
                sv[kf] = sa[qs][kf] + ma[kf];
                mx = fmaxf(mx, fmaxf(fmaxf(sv[kf][0], sv[kf][1]),
                                     fmaxf(sv[kf][2], sv[kf][3])));
            }
            mx = fmaxf(mx, __shfl_xor(mx, 16, 64));
            mx = fmaxf(mx, __shfl_xor(mx, 32, 64));
            if (!__all(mx <= m2[qs] + 11.54f)) { // defer-max
                const float mn = fmaxf(m2[qs], mx);
                const float corr = __builtin_amdgcn_exp2f(m2[qs] - mn);
#pragma unroll
                for (int vf = 0; vf < 4; vf++) oT[qs][vf] *= corr;
                lac[qs] *= corr;
                m2[qs] = mn;
            }
#pragma unroll
            for (int kf = 0; kf < 4; kf++) {
                bf16x4 pkk;
#pragma unroll
                for (int j = 0; j < 4; j++)
                    pkk[j] = (bf16)__builtin_amdgcn_exp2f(sv[kf][j] - m2[qs]);
                *(bf16x4*)&QPs[w*32 + qs*16 + r][kf*16 + g*4] = pkk;
            }
        }

        // ---- O^T += V^T * P^T ; l += ones * P^T ----
        __builtin_amdgcn_s_setprio(1);
#pragma unroll
        for (int ks = 0; ks < 2; ks++) {
            bf16x8 vfrag[4];
#pragma unroll
            for (int vf = 0; vf < 4; vf++)
                vfrag[vf] = *(const bf16x8*)&Vt[it][vf*16 + r][ks*32 + g*8];
#pragma unroll
            for (int qs = 0; qs < 2; qs++) {
                const bf16x8 pf = *(const bf16x8*)&QPs[w*32 + qs*16 + r][ks*32 + g*8];
                lac[qs] = __builtin_amdgcn_mfma_f32_16x16x32_bf16(
                    ones, pf, lac[qs], 0, 0, 0);
#pragma unroll
                for (int vf = 0; vf < 4; vf++)
                    oT[qs][vf] = __builtin_amdgcn_mfma_f32_16x16x32_bf16(
                        vfrag[vf], pf, oT[qs][vf], 0, 0, 0);
            }
        }
        __builtin_amdgcn_s_setprio(0);

        // ---- write prefetched tile into the other buffer (no barrier needed:
        //      all waves' reads of buf[it^1] were ordered by this iter's barrier)
        if (more) {
            *(bf16x8*)&Ks[it^1][srow][sc0]     = kr0;
            *(bf16x8*)&Ks[it^1][srow][sc0 + 8] = kr1;
            *(bf16x8*)&Vt[it^1][srow][sc0]     = vr0;
            *(bf16x8*)&Vt[it^1][srow][sc0 + 8] = vr1;
        }
    }

    // ---- epilogue: O^T lane-local per query; normalize & store ----
#pragma unroll
    for (int qs = 0; qs < 2; qs++) {
        const float inv = 1.0f / lac[qs][0];
        const int s = q0 + w*32 + qs*16 + r;
        bf16* dst = attn + ((size_t)(b*2048) + s) * 512 + h*64 + g*4;
#pragma unroll
        for (int vf = 0; vf < 4; vf++) {
            bf16x4 ov;
#pragma unroll
            for (int j = 0; j < 4; j++) ov[j] = (bf16)(oT[qs][vf][j] * inv);
            *(bf16x4*)(dst + vf*16) = ov;
        }
    }
}

// ---------------------------------------------------------------------------
extern "C" void kernel_launch(void* const* d_in, const int* in_sizes, int n_in,
                              void* d_out, int out_size, void* d_ws, size_t ws_size,
                              hipStream_t stream)
{
    const float* q    = (const float*)d_in[0];
    const float* k    = (const float*)d_in[1];
    const float* v    = (const float*)d_in[2];
    const int*   mask = (const int*)  d_in[3];
    const float* wq   = (const float*)d_in[4];
    const float* bq   = (const float*)d_in[5];
    const float* wk   = (const float*)d_in[6];
    const float* bk   = (const float*)d_in[7];
    const float* wv   = (const float*)d_in[8];
    const float* bv   = (const float*)d_in[9];
    const float* wd   = (const float*)d_in[10];
    const float* bd   = (const float*)d_in[11];
    float* out = (float*)d_out;

    const size_t NELEM = (size_t)4 * 2048 * 512;   // 4,194,304
    bf16* qp  = (bf16*)d_ws;
    bf16* kp  = qp + NELEM;
    bf16* vpT = kp + NELEM;                         // [B,H,64,S]
    bf16* ab  = vpT + NELEM;                        // merged attn output
    bf16* wt  = ab + NELEM;                         // 4 x 512x512 bf16

    prep_w<<<dim3(8, 8, 4), dim3(256), 0, stream>>>(wq, wk, wv, wd, wt);

    const float qscale = 0.125f * LOG2E;            // fold 1/sqrt(hd) and log2e
    dim3 gg(64, 4), gb(256);
    gemm_kernel<0><<<gg, gb, 0, stream>>>((const void*)q, wt + 0*262144, bq, (void*)qp,  qscale);
    gemm_kernel<0><<<gg, gb, 0, stream>>>((const void*)k, wt + 1*262144, bk, (void*)kp,  1.0f);
    gemm_kernel<2><<<gg, gb, 0, stream>>>((const void*)v, wt + 2*262144, bv, (void*)vpT, 1.0f);

    attn_kernel<<<dim3(32, 16), dim3(256), 0, stream>>>(qp, kp, vpT, mask, ab);

    gemm_kernel<1><<<gg, gb, 0, stream>>>((const void*)ab, wt + 3*262144, bd, (void*)out, 1.0f);
}

// Round 5
// 113.642 us; speedup vs baseline: 2.0452x; 1.3058x over previous
//
#include <hip/hip_runtime.h>
#include <hip/hip_bf16.h>
#include <cmath>

typedef __bf16 bf16;
typedef __attribute__((ext_vector_type(8))) __bf16 bf16x8;
typedef __attribute__((ext_vector_type(4))) __bf16 bf16x4;
typedef __attribute__((ext_vector_type(4))) float f32x4;

#define LOG2E 1.4426950408889634f

// ---------------------------------------------------------------------------
// prep_w: transpose + convert 4 weight matrices fp32 [512 k][512 n]
//         -> bf16 WT [512 n][512 k], one per blockIdx.z.
// ---------------------------------------------------------------------------
__global__ __launch_bounds__(256)
void prep_w(const float* __restrict__ w0, const float* __restrict__ w1,
            const float* __restrict__ w2, const float* __restrict__ w3,
            bf16* __restrict__ wt)
{
    const float* W = (blockIdx.z == 0) ? w0 : (blockIdx.z == 1) ? w1
                   : (blockIdx.z == 2) ? w2 : w3;
    bf16* WT = wt + (size_t)blockIdx.z * 512 * 512;

    __shared__ bf16 t[64][72];
    const int k0 = blockIdx.x * 64, n0 = blockIdx.y * 64;
    const int tid = threadIdx.x;
    {
        const int row = tid >> 2;            // k-local
        const int c0 = (tid & 3) * 16;       // n-local
        const float* src = W + (size_t)(k0 + row) * 512 + n0 + c0;
#pragma unroll
        for (int i = 0; i < 16; i += 4) {
            f32x4 f = *(const f32x4*)(src + i);
            t[c0 + i + 0][row] = (bf16)f[0];
            t[c0 + i + 1][row] = (bf16)f[1];
            t[c0 + i + 2][row] = (bf16)f[2];
            t[c0 + i + 3][row] = (bf16)f[3];
        }
    }
    __syncthreads();
    {
        const int nrow = tid >> 2;           // n-local
        const int c0 = (tid & 3) * 16;       // k-local
        bf16* dst = WT + (size_t)(n0 + nrow) * 512 + k0 + c0;
        *(bf16x8*)(dst)     = *(const bf16x8*)&t[nrow][c0];
        *(bf16x8*)(dst + 8) = *(const bf16x8*)&t[nrow][c0 + 8];
    }
}

// ---------------------------------------------------------------------------
// proj_kernel: all three projections in ONE launch (blockIdx.z = 0:q 1:k 2:v).
// C = (A[8192x512] * W + bias) [* qscale for z==0]
// z 0/1: bf16 head-split [B,H,S,64]; z==2: bf16 head-transposed [B,H,64,S].
// Tile 64x128, BK=64, 4 waves (2x2, each 32x64), reg-prefetch single-buffer.
// Grid (128, 4, 3) = 1536 blocks -> ~5-6 blocks/CU.
// ---------------------------------------------------------------------------
__global__ __launch_bounds__(256)
void proj_kernel(const float* __restrict__ qin, const float* __restrict__ kin,
                 const float* __restrict__ vin, const bf16* __restrict__ wt,
                 const float* __restrict__ bq, const float* __restrict__ bk,
                 const float* __restrict__ bv, bf16* __restrict__ qp,
                 bf16* __restrict__ kp, bf16* __restrict__ vpT)
{
    const int z = blockIdx.z;
    const float* A    = (z == 0) ? qin : (z == 1) ? kin : vin;
    const bf16* WT    = wt + (size_t)z * 262144;
    const float* bias = (z == 0) ? bq : (z == 1) ? bk : bv;
    const float scale = (z == 0) ? 0.125f * LOG2E : 1.0f;

    const int row0 = blockIdx.x * 64;
    const int col0 = blockIdx.y * 128;
    const int tid = threadIdx.x;
    const int wave = tid >> 6, lane = tid & 63;
    const int wr = wave >> 1, wc = wave & 1;     // wave tile 32 x 64
    const int g = lane >> 4, r = lane & 15;

    __shared__ bf16 As[64][72];
    __shared__ bf16 Bs[128][72];

    const int arow = tid >> 2, ak0 = (tid & 3) * 16;
    const int brow = tid >> 1, bk0 = (tid & 1) * 32;

    f32x4 a0, a1, a2, a3;
    bf16x8 b0, b1, b2, b3;
    {
        const float* asrc = A + (size_t)(row0 + arow) * 512 + ak0;
        a0 = *(const f32x4*)(asrc);     a1 = *(const f32x4*)(asrc + 4);
        a2 = *(const f32x4*)(asrc + 8); a3 = *(const f32x4*)(asrc + 12);
        const bf16* bsrc = WT + (size_t)(col0 + brow) * 512 + bk0;
        b0 = *(const bf16x8*)(bsrc);      b1 = *(const bf16x8*)(bsrc + 8);
        b2 = *(const bf16x8*)(bsrc + 16); b3 = *(const bf16x8*)(bsrc + 24);
    }

    f32x4 acc[2][4] = {};

    for (int kt = 0; kt < 512; kt += 64) {
        {   // write staged regs -> LDS (fp32 A converted here)
            bf16x8 v0, v1;
#pragma unroll
            for (int i = 0; i < 4; i++) {
                v0[i] = (bf16)a0[i]; v0[4+i] = (bf16)a1[i];
                v1[i] = (bf16)a2[i]; v1[4+i] = (bf16)a3[i];
            }
            *(bf16x8*)&As[arow][ak0]     = v0;
            *(bf16x8*)&As[arow][ak0 + 8] = v1;
            *(bf16x8*)&Bs[brow][bk0]      = b0;
            *(bf16x8*)&Bs[brow][bk0 +  8] = b1;
            *(bf16x8*)&Bs[brow][bk0 + 16] = b2;
            *(bf16x8*)&Bs[brow][bk0 + 24] = b3;
        }
        __syncthreads();

        if (kt + 64 < 512) {                 // prefetch next K-slab
            const float* asrc = A + (size_t)(row0 + arow) * 512 + kt + 64 + ak0;
            a0 = *(const f32x4*)(asrc);     a1 = *(const f32x4*)(asrc + 4);
            a2 = *(const f32x4*)(asrc + 8); a3 = *(const f32x4*)(asrc + 12);
            const bf16* bsrc = WT + (size_t)(col0 + brow) * 512 + kt + 64 + bk0;
            b0 = *(const bf16x8*)(bsrc);      b1 = *(const bf16x8*)(bsrc + 8);
            b2 = *(const bf16x8*)(bsrc + 16); b3 = *(const bf16x8*)(bsrc + 24);
        }

#pragma unroll
        for (int kk = 0; kk < 64; kk += 32) {
            bf16x8 af[2], bfr[4];
#pragma unroll
            for (int mf = 0; mf < 2; mf++)
                af[mf] = *(const bf16x8*)&As[wr*32 + mf*16 + r][kk + g*8];
#pragma unroll
            for (int nf = 0; nf < 4; nf++)
                bfr[nf] = *(const bf16x8*)&Bs[wc*64 + nf*16 + r][kk + g*8];
#pragma unroll
            for (int mf = 0; mf < 2; mf++)
#pragma unroll
                for (int nf = 0; nf < 4; nf++)
                    acc[mf][nf] = __builtin_amdgcn_mfma_f32_16x16x32_bf16(
                        af[mf], bfr[nf], acc[mf][nf], 0, 0, 0);
        }
        __syncthreads();
    }

    // ---- epilogue ----
#pragma unroll
    for (int mf = 0; mf < 2; mf++) {
#pragma unroll
        for (int nf = 0; nf < 4; nf++) {
            const int rbase = row0 + wr*32 + mf*16 + g*4;
            const int ccol  = col0 + wc*64 + nf*16 + r;
            const float bi = bias[ccol];
            const int h = ccol >> 6, hd = ccol & 63;
            if (z < 2) {
                bf16* C = (z == 0) ? qp : kp;
#pragma unroll
                for (int j = 0; j < 4; j++) {
                    const int rrow = rbase + j;
                    const int b = rrow >> 11, s = rrow & 2047;
                    C[(((size_t)(b*8 + h) * 2048) + s) * 64 + hd] =
                        (bf16)((acc[mf][nf][j] + bi) * scale);
                }
            } else {
                const int b = rbase >> 11, s = rbase & 2047;
                bf16x4 pk;
#pragma unroll
                for (int j = 0; j < 4; j++) pk[j] = (bf16)(acc[mf][nf][j] + bi);
                *(bf16x4*)(vpT + ((size_t)(b*8 + h) * 64 + hd) * 2048 + s) = pk;
            }
        }
    }
}

// ---------------------------------------------------------------------------
// dense_kernel: final projection, A bf16 [8192,512], out fp32 [8192,512].
// Same 64x128 / BK=64 structure. Grid (128, 4) = 512 blocks.
// ---------------------------------------------------------------------------
__global__ __launch_bounds__(256)
void dense_kernel(const bf16* __restrict__ ab, const bf16* __restrict__ WT,
                  const float* __restrict__ bias, float* __restrict__ out)
{
    const int row0 = blockIdx.x * 64;
    const int col0 = blockIdx.y * 128;
    const int tid = threadIdx.x;
    const int wave = tid >> 6, lane = tid & 63;
    const int wr = wave >> 1, wc = wave & 1;
    const int g = lane >> 4, r = lane & 15;

    __shared__ bf16 As[64][72];
    __shared__ bf16 Bs[128][72];

    const int arow = tid >> 2, ak0 = (tid & 3) * 16;
    const int brow = tid >> 1, bk0 = (tid & 1) * 32;

    bf16x8 aR0, aR1, b0, b1, b2, b3;
    {
        const bf16* asrc = ab + (size_t)(row0 + arow) * 512 + ak0;
        aR0 = *(const bf16x8*)(asrc); aR1 = *(const bf16x8*)(asrc + 8);
        const bf16* bsrc = WT + (size_t)(col0 + brow) * 512 + bk0;
        b0 = *(const bf16x8*)(bsrc);      b1 = *(const bf16x8*)(bsrc + 8);
        b2 = *(const bf16x8*)(bsrc + 16); b3 = *(const bf16x8*)(bsrc + 24);
    }

    f32x4 acc[2][4] = {};

    for (int kt = 0; kt < 512; kt += 64) {
        *(bf16x8*)&As[arow][ak0]     = aR0;
        *(bf16x8*)&As[arow][ak0 + 8] = aR1;
        *(bf16x8*)&Bs[brow][bk0]      = b0;
        *(bf16x8*)&Bs[brow][bk0 +  8] = b1;
        *(bf16x8*)&Bs[brow][bk0 + 16] = b2;
        *(bf16x8*)&Bs[brow][bk0 + 24] = b3;
        __syncthreads();

        if (kt + 64 < 512) {
            const bf16* asrc = ab + (size_t)(row0 + arow) * 512 + kt + 64 + ak0;
            aR0 = *(const bf16x8*)(asrc); aR1 = *(const bf16x8*)(asrc + 8);
            const bf16* bsrc = WT + (size_t)(col0 + brow) * 512 + kt + 64 + bk0;
            b0 = *(const bf16x8*)(bsrc);      b1 = *(const bf16x8*)(bsrc + 8);
            b2 = *(const bf16x8*)(bsrc + 16); b3 = *(const bf16x8*)(bsrc + 24);
        }

#pragma unroll
        for (int kk = 0; kk < 64; kk += 32) {
            bf16x8 af[2], bfr[4];
#pragma unroll
            for (int mf = 0; mf < 2; mf++)
                af[mf] = *(const bf16x8*)&As[wr*32 + mf*16 + r][kk + g*8];
#pragma unroll
            for (int nf = 0; nf < 4; nf++)
                bfr[nf] = *(const bf16x8*)&Bs[wc*64 + nf*16 + r][kk + g*8];
#pragma unroll
            for (int mf = 0; mf < 2; mf++)
#pragma unroll
                for (int nf = 0; nf < 4; nf++)
                    acc[mf][nf] = __builtin_amdgcn_mfma_f32_16x16x32_bf16(
                        af[mf], bfr[nf], acc[mf][nf], 0, 0, 0);
        }
        __syncthreads();
    }

#pragma unroll
    for (int mf = 0; mf < 2; mf++) {
#pragma unroll
        for (int nf = 0; nf < 4; nf++) {
            const int rbase = row0 + wr*32 + mf*16 + g*4;
            const int ccol  = col0 + wc*64 + nf*16 + r;
            const float bi = bias[ccol];
#pragma unroll
            for (int j = 0; j < 4; j++)
                out[(size_t)(rbase + j) * 512 + ccol] = acc[mf][nf][j] + bi;
        }
    }
}

// ---------------------------------------------------------------------------
// Flash attention, swapped-operand, 2 q-subtiles per wave (32 q/wave).
// Block = (b,h) x 128 queries, 4 waves. K/V double-buffered in LDS, one
// barrier per tile. exp2-domain softmax (Q pre-scaled). l via ones-MFMA.
// Lazy defer-max: per-lane local vote; shuffle reduce only on trigger.
// ---------------------------------------------------------------------------
__global__ __launch_bounds__(256)
void attn_kernel(const bf16* __restrict__ qp, const bf16* __restrict__ kp,
                 const bf16* __restrict__ vpT, const int* __restrict__ mask,
                 bf16* __restrict__ attn)
{
    const int bh = blockIdx.x;           // 0..31
    const int qt = blockIdx.y;           // 0..15
    const int b = bh >> 3, h = bh & 7;
    const int tid = threadIdx.x;
    const int w = tid >> 6, lane = tid & 63;
    const int g = (lane >> 4) & 3, r = lane & 15;

    __shared__ bf16 QPs[128][72];                // Q tile, then reused as P
    __shared__ bf16 Ks[2][64][72];               // [buf][key][hd]
    __shared__ bf16 Vt[2][64][72];               // [buf][hd][key]
    __shared__ __align__(16) float madd2[2048];  // mask * -1e9*log2e

    const size_t head_base = (size_t)(b*8 + h) * 2048 * 64;
    const int q0 = qt * 128;
    const bf16* kbase = kp  + head_base;
    const bf16* vbase = vpT + head_base;

    // ---- stage mask additive (whole row, once) ----
    {
        const int4* m4 = (const int4*)(mask + b * 2048);
#pragma unroll
        for (int i = 0; i < 2; i++) {
            const int4 mv = m4[tid*2 + i];
            f32x4 f;
            f[0] = mv.x ? -1.4426950e9f : 0.f;
            f[1] = mv.y ? -1.4426950e9f : 0.f;
            f[2] = mv.z ? -1.4426950e9f : 0.f;
            f[3] = mv.w ? -1.4426950e9f : 0.f;
            *(f32x4*)&madd2[tid*8 + i*4] = f;
        }
    }
    // ---- load Q tile (wave w writes exactly rows [32w,32w+32) it reads) ----
    {
        const int row = tid >> 1;
        const int c0 = (tid & 1) * 32;
        const bf16* src = qp + head_base + (size_t)(q0 + row) * 64 + c0;
        *(bf16x8*)&QPs[row][c0]      = *(const bf16x8*)(src);
        *(bf16x8*)&QPs[row][c0 +  8] = *(const bf16x8*)(src + 8);
        *(bf16x8*)&QPs[row][c0 + 16] = *(const bf16x8*)(src + 16);
        *(bf16x8*)&QPs[row][c0 + 24] = *(const bf16x8*)(src + 24);
    }
    bf16x8 qf[2][2];
#pragma unroll
    for (int qs = 0; qs < 2; qs++)
#pragma unroll
        for (int ks = 0; ks < 2; ks++)
            qf[qs][ks] = *(const bf16x8*)&QPs[w*32 + qs*16 + r][ks*32 + g*8];

    // ---- staging lane mapping + preload tile 0 into buf 0 ----
    const int srow = tid >> 2;
    const int sc0  = (tid & 3) * 16;
    bf16x8 kr0, kr1, vr0, vr1;
    kr0 = *(const bf16x8*)(kbase + (size_t)srow * 64 + sc0);
    kr1 = *(const bf16x8*)(kbase + (size_t)srow * 64 + sc0 + 8);
    vr0 = *(const bf16x8*)(vbase + (size_t)srow * 2048 + sc0);
    vr1 = *(const bf16x8*)(vbase + (size_t)srow * 2048 + sc0 + 8);
    *(bf16x8*)&Ks[0][srow][sc0]     = kr0;
    *(bf16x8*)&Ks[0][srow][sc0 + 8] = kr1;
    *(bf16x8*)&Vt[0][srow][sc0]     = vr0;
    *(bf16x8*)&Vt[0][srow][sc0 + 8] = vr1;

    float m2[2] = {-INFINITY, -INFINITY};
    f32x4 oT[2][4] = {};                         // O^T per qsub
    f32x4 lac[2] = {};                           // l via ones-MFMA row
    bf16x8 ones;
#pragma unroll
    for (int i = 0; i < 8; i++) ones[i] = (bf16)1.0f;

    int it = 0;
    for (int kt = 0; kt < 2048; kt += 64, it ^= 1) {
        __syncthreads();                         // buf[it] ready for all
        const bool more = (kt + 64) < 2048;
        if (more) {                              // prefetch next tile to regs
            kr0 = *(const bf16x8*)(kbase + (size_t)(kt+64+srow)*64 + sc0);
            kr1 = *(const bf16x8*)(kbase + (size_t)(kt+64+srow)*64 + sc0 + 8);
            vr0 = *(const bf16x8*)(vbase + (size_t)srow*2048 + kt+64 + sc0);
            vr1 = *(const bf16x8*)(vbase + (size_t)srow*2048 + kt+64 + sc0 + 8);
        }

        // ---- S^T = K*Q^T ----
        f32x4 sa[2][4] = {};
        __builtin_amdgcn_s_setprio(1);
#pragma unroll
        for (int ks = 0; ks < 2; ks++) {
            bf16x8 kfrag[4];
#pragma unroll
            for (int kf = 0; kf < 4; kf++)
                kfrag[kf] = *(const bf16x8*)&Ks[it][kf*16 + r][ks*32 + g*8];
#pragma unroll
            for (int qs = 0; qs < 2; qs++)
#pragma unroll
                for (int kf = 0; kf < 4; kf++)
                    sa[qs][kf] = __builtin_amdgcn_mfma_f32_16x16x32_bf16(
                        kfrag[kf], qf[qs][ks], sa[qs][kf], 0, 0, 0);
        }
        __builtin_amdgcn_s_setprio(0);

        f32x4 ma[4];
#pragma unroll
        for (int kf = 0; kf < 4; kf++)
            ma[kf] = *(const f32x4*)&madd2[kt + kf*16 + g*4];

        // ---- per-lane softmax (exp2 domain), P -> LDS ----
#pragma unroll
        for (int qs = 0; qs < 2; qs++) {
            f32x4 sv[4];
            float mx = -INFINITY;
#pragma unroll
            for (int kf = 0; kf < 4; kf++) {
                sv[kf] = sa[qs][kf] + ma[kf];
                mx = fmaxf(mx, fmaxf(fmaxf(sv[kf][0], sv[kf][1]),
                                     fmaxf(sv[kf][2], sv[kf][3])));
            }
            // lazy defer-max: vote on LOCAL max (conservative: if all local
            // maxima are below m+THR, the global max is too). Shuffle-reduce
            // only on trigger (first tile always triggers: m = -inf).
            if (!__all(mx <= m2[qs] + 11.54f)) {
                mx = fmaxf(mx, __shfl_xor(mx, 16, 64));
                mx = fmaxf(mx, __shfl_xor(mx, 32, 64));
                const float mn = fmaxf(m2[qs], mx);
                const float corr = __builtin_amdgcn_exp2f(m2[qs] - mn);
#pragma unroll
                for (int vf = 0; vf < 4; vf++) oT[qs][vf] *= corr;
                lac[qs] *= corr;
                m2[qs] = mn;
            }
#pragma unroll
            for (int kf = 0; kf < 4; kf++) {
                bf16x4 pkk;
#pragma unroll
                for (int j = 0; j < 4; j++)
                    pkk[j] = (bf16)__builtin_amdgcn_exp2f(sv[kf][j] - m2[qs]);
                *(bf16x4*)&QPs[w*32 + qs*16 + r][kf*16 + g*4] = pkk;
            }
        }

        // ---- O^T += V^T * P^T ; l += ones * P^T ----
        __builtin_amdgcn_s_setprio(1);
#pragma unroll
        for (int ks = 0; ks < 2; ks++) {
            bf16x8 vfrag[4];
#pragma unroll
            for (int vf = 0; vf < 4; vf++)
                vfrag[vf] = *(const bf16x8*)&Vt[it][vf*16 + r][ks*32 + g*8];
#pragma unroll
            for (int qs = 0; qs < 2; qs++) {
                const bf16x8 pf = *(const bf16x8*)&QPs[w*32 + qs*16 + r][ks*32 + g*8];
                lac[qs] = __builtin_amdgcn_mfma_f32_16x16x32_bf16(
                    ones, pf, lac[qs], 0, 0, 0);
#pragma unroll
                for (int vf = 0; vf < 4; vf++)
                    oT[qs][vf] = __builtin_amdgcn_mfma_f32_16x16x32_bf16(
                        vfrag[vf], pf, oT[qs][vf], 0, 0, 0);
            }
        }
        __builtin_amdgcn_s_setprio(0);

        // ---- write prefetched tile into the other buffer ----
        if (more) {
            *(bf16x8*)&Ks[it^1][srow][sc0]     = kr0;
            *(bf16x8*)&Ks[it^1][srow][sc0 + 8] = kr1;
            *(bf16x8*)&Vt[it^1][srow][sc0]     = vr0;
            *(bf16x8*)&Vt[it^1][srow][sc0 + 8] = vr1;
        }
    }

    // ---- epilogue ----
#pragma unroll
    for (int qs = 0; qs < 2; qs++) {
        const float inv = 1.0f / lac[qs][0];
        const int s = q0 + w*32 + qs*16 + r;
        bf16* dst = attn + ((size_t)(b*2048) + s) * 512 + h*64 + g*4;
#pragma unroll
        for (int vf = 0; vf < 4; vf++) {
            bf16x4 ov;
#pragma unroll
            for (int j = 0; j < 4; j++) ov[j] = (bf16)(oT[qs][vf][j] * inv);
            *(bf16x4*)(dst + vf*16) = ov;
        }
    }
}

// ---------------------------------------------------------------------------
extern "C" void kernel_launch(void* const* d_in, const int* in_sizes, int n_in,
                              void* d_out, int out_size, void* d_ws, size_t ws_size,
                              hipStream_t stream)
{
    const float* q    = (const float*)d_in[0];
    const float* k    = (const float*)d_in[1];
    const float* v    = (const float*)d_in[2];
    const int*   mask = (const int*)  d_in[3];
    const float* wq   = (const float*)d_in[4];
    const float* bq   = (const float*)d_in[5];
    const float* wk   = (const float*)d_in[6];
    const float* bk   = (const float*)d_in[7];
    const float* wv   = (const float*)d_in[8];
    const float* bv   = (const float*)d_in[9];
    const float* wd   = (const float*)d_in[10];
    const float* bd   = (const float*)d_in[11];
    float* out = (float*)d_out;

    const size_t NELEM = (size_t)4 * 2048 * 512;   // 4,194,304
    bf16* qp  = (bf16*)d_ws;
    bf16* kp  = qp + NELEM;
    bf16* vpT = kp + NELEM;                         // [B,H,64,S]
    bf16* ab  = vpT + NELEM;                        // merged attn output
    bf16* wt  = ab + NELEM;                         // 4 x 512x512 bf16

    prep_w<<<dim3(8, 8, 4), dim3(256), 0, stream>>>(wq, wk, wv, wd, wt);

    proj_kernel<<<dim3(128, 4, 3), dim3(256), 0, stream>>>(
        q, k, v, wt, bq, bk, bv, qp, kp, vpT);

    attn_kernel<<<dim3(32, 16), dim3(256), 0, stream>>>(qp, kp, vpT, mask, ab);

    dense_kernel<<<dim3(128, 4), dim3(256), 0, stream>>>(
        ab, wt + 3*262144, bd, out);
}

// Round 6
// 105.802 us; speedup vs baseline: 2.1968x; 1.0741x over previous
//
#include <hip/hip_runtime.h>
#include <hip/hip_bf16.h>
#include <cmath>

typedef __bf16 bf16;
typedef __attribute__((ext_vector_type(8))) __bf16 bf16x8;
typedef __attribute__((ext_vector_type(4))) __bf16 bf16x4;
typedef __attribute__((ext_vector_type(4))) float f32x4;
typedef __attribute__((ext_vector_type(16))) float f32x16;

#define LOG2E 1.4426950408889634f

// ---------------------------------------------------------------------------
// prep_w: transpose + convert 4 weight matrices fp32 [512 k][512 n]
//         -> bf16 WT [512 n][512 k], one per blockIdx.z.
// ---------------------------------------------------------------------------
__global__ __launch_bounds__(256)
void prep_w(const float* __restrict__ w0, const float* __restrict__ w1,
            const float* __restrict__ w2, const float* __restrict__ w3,
            bf16* __restrict__ wt)
{
    const float* W = (blockIdx.z == 0) ? w0 : (blockIdx.z == 1) ? w1
                   : (blockIdx.z == 2) ? w2 : w3;
    bf16* WT = wt + (size_t)blockIdx.z * 512 * 512;

    __shared__ bf16 t[64][72];
    const int k0 = blockIdx.x * 64, n0 = blockIdx.y * 64;
    const int tid = threadIdx.x;
    {
        const int row = tid >> 2;            // k-local
        const int c0 = (tid & 3) * 16;       // n-local
        const float* src = W + (size_t)(k0 + row) * 512 + n0 + c0;
#pragma unroll
        for (int i = 0; i < 16; i += 4) {
            f32x4 f = *(const f32x4*)(src + i);
            t[c0 + i + 0][row] = (bf16)f[0];
            t[c0 + i + 1][row] = (bf16)f[1];
            t[c0 + i + 2][row] = (bf16)f[2];
            t[c0 + i + 3][row] = (bf16)f[3];
        }
    }
    __syncthreads();
    {
        const int nrow = tid >> 2;           // n-local
        const int c0 = (tid & 3) * 16;       // k-local
        bf16* dst = WT + (size_t)(n0 + nrow) * 512 + k0 + c0;
        *(bf16x8*)(dst)     = *(const bf16x8*)&t[nrow][c0];
        *(bf16x8*)(dst + 8) = *(const bf16x8*)&t[nrow][c0 + 8];
    }
}

// ---------------------------------------------------------------------------
// proj_kernel: all three projections in ONE launch (blockIdx.z = 0:q 1:k 2:v).
// ---------------------------------------------------------------------------
__global__ __launch_bounds__(256)
void proj_kernel(const float* __restrict__ qin, const float* __restrict__ kin,
                 const float* __restrict__ vin, const bf16* __restrict__ wt,
                 const float* __restrict__ bq, const float* __restrict__ bk,
                 const float* __restrict__ bv, bf16* __restrict__ qp,
                 bf16* __restrict__ kp, bf16* __restrict__ vpT)
{
    const int z = blockIdx.z;
    const float* A    = (z == 0) ? qin : (z == 1) ? kin : vin;
    const bf16* WT    = wt + (size_t)z * 262144;
    const float* bias = (z == 0) ? bq : (z == 1) ? bk : bv;
    const float scale = (z == 0) ? 0.125f * LOG2E : 1.0f;

    const int row0 = blockIdx.x * 64;
    const int col0 = blockIdx.y * 128;
    const int tid = threadIdx.x;
    const int wave = tid >> 6, lane = tid & 63;
    const int wr = wave >> 1, wc = wave & 1;
    const int g = lane >> 4, r = lane & 15;

    __shared__ bf16 As[64][72];
    __shared__ bf16 Bs[128][72];

    const int arow = tid >> 2, ak0 = (tid & 3) * 16;
    const int brow = tid >> 1, bk0 = (tid & 1) * 32;

    f32x4 a0, a1, a2, a3;
    bf16x8 b0, b1, b2, b3;
    {
        const float* asrc = A + (size_t)(row0 + arow) * 512 + ak0;
        a0 = *(const f32x4*)(asrc);     a1 = *(const f32x4*)(asrc + 4);
        a2 = *(const f32x4*)(asrc + 8); a3 = *(const f32x4*)(asrc + 12);
        const bf16* bsrc = WT + (size_t)(col0 + brow) * 512 + bk0;
        b0 = *(const bf16x8*)(bsrc);      b1 = *(const bf16x8*)(bsrc + 8);
        b2 = *(const bf16x8*)(bsrc + 16); b3 = *(const bf16x8*)(bsrc + 24);
    }

    f32x4 acc[2][4] = {};

    for (int kt = 0; kt < 512; kt += 64) {
        {
            bf16x8 v0, v1;
#pragma unroll
            for (int i = 0; i < 4; i++) {
                v0[i] = (bf16)a0[i]; v0[4+i] = (bf16)a1[i];
                v1[i] = (bf16)a2[i]; v1[4+i] = (bf16)a3[i];
            }
            *(bf16x8*)&As[arow][ak0]     = v0;
            *(bf16x8*)&As[arow][ak0 + 8] = v1;
            *(bf16x8*)&Bs[brow][bk0]      = b0;
            *(bf16x8*)&Bs[brow][bk0 +  8] = b1;
            *(bf16x8*)&Bs[brow][bk0 + 16] = b2;
            *(bf16x8*)&Bs[brow][bk0 + 24] = b3;
        }
        __syncthreads();

        if (kt + 64 < 512) {
            const float* asrc = A + (size_t)(row0 + arow) * 512 + kt + 64 + ak0;
            a0 = *(const f32x4*)(asrc);     a1 = *(const f32x4*)(asrc + 4);
            a2 = *(const f32x4*)(asrc + 8); a3 = *(const f32x4*)(asrc + 12);
            const bf16* bsrc = WT + (size_t)(col0 + brow) * 512 + kt + 64 + bk0;
            b0 = *(const bf16x8*)(bsrc);      b1 = *(const bf16x8*)(bsrc + 8);
            b2 = *(const bf16x8*)(bsrc + 16); b3 = *(const bf16x8*)(bsrc + 24);
        }

#pragma unroll
        for (int kk = 0; kk < 64; kk += 32) {
            bf16x8 af[2], bfr[4];
#pragma unroll
            for (int mf = 0; mf < 2; mf++)
                af[mf] = *(const bf16x8*)&As[wr*32 + mf*16 + r][kk + g*8];
#pragma unroll
            for (int nf = 0; nf < 4; nf++)
                bfr[nf] = *(const bf16x8*)&Bs[wc*64 + nf*16 + r][kk + g*8];
#pragma unroll
            for (int mf = 0; mf < 2; mf++)
#pragma unroll
                for (int nf = 0; nf < 4; nf++)
                    acc[mf][nf] = __builtin_amdgcn_mfma_f32_16x16x32_bf16(
                        af[mf], bfr[nf], acc[mf][nf], 0, 0, 0);
        }
        __syncthreads();
    }

#pragma unroll
    for (int mf = 0; mf < 2; mf++) {
#pragma unroll
        for (int nf = 0; nf < 4; nf++) {
            const int rbase = row0 + wr*32 + mf*16 + g*4;
            const int ccol  = col0 + wc*64 + nf*16 + r;
            const float bi = bias[ccol];
            const int h = ccol >> 6, hd = ccol & 63;
            if (z < 2) {
                bf16* C = (z == 0) ? qp : kp;
#pragma unroll
                for (int j = 0; j < 4; j++) {
                    const int rrow = rbase + j;
                    const int b = rrow >> 11, s = rrow & 2047;
                    C[(((size_t)(b*8 + h) * 2048) + s) * 64 + hd] =
                        (bf16)((acc[mf][nf][j] + bi) * scale);
                }
            } else {
                const int b = rbase >> 11, s = rbase & 2047;
                bf16x4 pk;
#pragma unroll
                for (int j = 0; j < 4; j++) pk[j] = (bf16)(acc[mf][nf][j] + bi);
                *(bf16x4*)(vpT + ((size_t)(b*8 + h) * 64 + hd) * 2048 + s) = pk;
            }
        }
    }
}

// ---------------------------------------------------------------------------
// dense_kernel: final projection, A bf16 [8192,512], out fp32 [8192,512].
// ---------------------------------------------------------------------------
__global__ __launch_bounds__(256)
void dense_kernel(const bf16* __restrict__ ab, const bf16* __restrict__ WT,
                  const float* __restrict__ bias, float* __restrict__ out)
{
    const int row0 = blockIdx.x * 64;
    const int col0 = blockIdx.y * 128;
    const int tid = threadIdx.x;
    const int wave = tid >> 6, lane = tid & 63;
    const int wr = wave >> 1, wc = wave & 1;
    const int g = lane >> 4, r = lane & 15;

    __shared__ bf16 As[64][72];
    __shared__ bf16 Bs[128][72];

    const int arow = tid >> 2, ak0 = (tid & 3) * 16;
    const int brow = tid >> 1, bk0 = (tid & 1) * 32;

    bf16x8 aR0, aR1, b0, b1, b2, b3;
    {
        const bf16* asrc = ab + (size_t)(row0 + arow) * 512 + ak0;
        aR0 = *(const bf16x8*)(asrc); aR1 = *(const bf16x8*)(asrc + 8);
        const bf16* bsrc = WT + (size_t)(col0 + brow) * 512 + bk0;
        b0 = *(const bf16x8*)(bsrc);      b1 = *(const bf16x8*)(bsrc + 8);
        b2 = *(const bf16x8*)(bsrc + 16); b3 = *(const bf16x8*)(bsrc + 24);
    }

    f32x4 acc[2][4] = {};

    for (int kt = 0; kt < 512; kt += 64) {
        *(bf16x8*)&As[arow][ak0]     = aR0;
        *(bf16x8*)&As[arow][ak0 + 8] = aR1;
        *(bf16x8*)&Bs[brow][bk0]      = b0;
        *(bf16x8*)&Bs[brow][bk0 +  8] = b1;
        *(bf16x8*)&Bs[brow][bk0 + 16] = b2;
        *(bf16x8*)&Bs[brow][bk0 + 24] = b3;
        __syncthreads();

        if (kt + 64 < 512) {
            const bf16* asrc = ab + (size_t)(row0 + arow) * 512 + kt + 64 + ak0;
            aR0 = *(const bf16x8*)(asrc); aR1 = *(const bf16x8*)(asrc + 8);
            const bf16* bsrc = WT + (size_t)(col0 + brow) * 512 + kt + 64 + bk0;
            b0 = *(const bf16x8*)(bsrc);      b1 = *(const bf16x8*)(bsrc + 8);
            b2 = *(const bf16x8*)(bsrc + 16); b3 = *(const bf16x8*)(bsrc + 24);
        }

#pragma unroll
        for (int kk = 0; kk < 64; kk += 32) {
            bf16x8 af[2], bfr[4];
#pragma unroll
            for (int mf = 0; mf < 2; mf++)
                af[mf] = *(const bf16x8*)&As[wr*32 + mf*16 + r][kk + g*8];
#pragma unroll
            for (int nf = 0; nf < 4; nf++)
                bfr[nf] = *(const bf16x8*)&Bs[wc*64 + nf*16 + r][kk + g*8];
#pragma unroll
            for (int mf = 0; mf < 2; mf++)
#pragma unroll
                for (int nf = 0; nf < 4; nf++)
                    acc[mf][nf] = __builtin_amdgcn_mfma_f32_16x16x32_bf16(
                        af[mf], bfr[nf], acc[mf][nf], 0, 0, 0);
        }
        __syncthreads();
    }

#pragma unroll
    for (int mf = 0; mf < 2; mf++) {
#pragma unroll
        for (int nf = 0; nf < 4; nf++) {
            const int rbase = row0 + wr*32 + mf*16 + g*4;
            const int ccol  = col0 + wc*64 + nf*16 + r;
            const float bi = bias[ccol];
#pragma unroll
            for (int j = 0; j < 4; j++)
                out[(size_t)(rbase + j) * 512 + ccol] = acc[mf][nf][j] + bi;
        }
    }
}

// ---------------------------------------------------------------------------
// Flash attention, 32x32 MFMA, fully in-register P via permlane32_swap.
// Wave owns 32 queries (q = q0 + w*32 + (lane&31)). S^T = mfma32(K, Q):
// lane (hi,c) holds scores for q=c at keys {j + 8t + 4hi} per 32-key group.
// P packed to bf16 pairs (v_cvt_pk_bf16_f32) -> quadrant regs Z[t]; PV
// B-frags built by v_permlane32_swap_b32 (hi(dst) <-> lo(src)): P never
// touches LDS. l = in-lane psum + 1 shuffle. Defer-max lazy vote (THR=11.54
// in log2 domain). K/V double-buffered LDS, one barrier/tile.
// ---------------------------------------------------------------------------
__global__ __launch_bounds__(256)
void attn_kernel(const bf16* __restrict__ qp, const bf16* __restrict__ kp,
                 const bf16* __restrict__ vpT, const int* __restrict__ mask,
                 bf16* __restrict__ attn)
{
    const int bh = blockIdx.x;           // 0..31
    const int qt = blockIdx.y;           // 0..15
    const int b = bh >> 3, h = bh & 7;
    const int tid = threadIdx.x;
    const int w = tid >> 6, lane = tid & 63;
    const int c = lane & 31;             // query column
    const int hi = lane >> 5;            // half-wave id

    __shared__ bf16 Ks[2][64][72];               // [buf][key][hd]
    __shared__ bf16 Vt[2][64][72];               // [buf][hd][key]
    __shared__ __align__(16) float madd2[2048];  // mask * -1e9*log2e

    const size_t head_base = (size_t)(b*8 + h) * 2048 * 64;
    const int q0 = qt * 128;
    const bf16* kbase = kp  + head_base;
    const bf16* vbase = vpT + head_base;

    // ---- stage mask additive (whole row, once) ----
    {
        const int4* m4 = (const int4*)(mask + b * 2048);
#pragma unroll
        for (int i = 0; i < 2; i++) {
            const int4 mv = m4[tid*2 + i];
            f32x4 f;
            f[0] = mv.x ? -1.4426950e9f : 0.f;
            f[1] = mv.y ? -1.4426950e9f : 0.f;
            f[2] = mv.z ? -1.4426950e9f : 0.f;
            f[3] = mv.w ? -1.4426950e9f : 0.f;
            *(f32x4*)&madd2[tid*8 + i*4] = f;
        }
    }

    // ---- Q fragments direct from global: B[k=hd][col=q] ----
    bf16x8 qf[4];
    {
        const bf16* qsrc = qp + head_base + (size_t)(q0 + w*32 + c) * 64 + hi*8;
#pragma unroll
        for (int kstep = 0; kstep < 4; kstep++)
            qf[kstep] = *(const bf16x8*)(qsrc + kstep*16);
    }

    // ---- staging lane mapping + preload tile 0 into buf 0 ----
    const int srow = tid >> 2;
    const int sc0  = (tid & 3) * 16;
    bf16x8 kr0, kr1, vr0, vr1;
    kr0 = *(const bf16x8*)(kbase + (size_t)srow * 64 + sc0);
    kr1 = *(const bf16x8*)(kbase + (size_t)srow * 64 + sc0 + 8);
    vr0 = *(const bf16x8*)(vbase + (size_t)srow * 2048 + sc0);
    vr1 = *(const bf16x8*)(vbase + (size_t)srow * 2048 + sc0 + 8);
    *(bf16x8*)&Ks[0][srow][sc0]     = kr0;
    *(bf16x8*)&Ks[0][srow][sc0 + 8] = kr1;
    *(bf16x8*)&Vt[0][srow][sc0]     = vr0;
    *(bf16x8*)&Vt[0][srow][sc0 + 8] = vr1;

    float m_run = -INFINITY, l_run = 0.f;
    f32x16 oT0 = {}, oT1 = {};           // O^T: d = dg*32 + 8t + 4hi + j, q = c

    int it = 0;
    for (int kt = 0; kt < 2048; kt += 64, it ^= 1) {
        __syncthreads();                 // buf[it] ready for all
        const bool more = (kt + 64) < 2048;
        if (more) {
            kr0 = *(const bf16x8*)(kbase + (size_t)(kt+64+srow)*64 + sc0);
            kr1 = *(const bf16x8*)(kbase + (size_t)(kt+64+srow)*64 + sc0 + 8);
            vr0 = *(const bf16x8*)(vbase + (size_t)srow*2048 + kt+64 + sc0);
            vr1 = *(const bf16x8*)(vbase + (size_t)srow*2048 + kt+64 + sc0 + 8);
        }

        // ---- S^T = K * Q^T (two 32-key groups) ----
        f32x16 sa0 = {}, sa1 = {};
        __builtin_amdgcn_s_setprio(1);
#pragma unroll
        for (int kstep = 0; kstep < 4; kstep++) {
            const bf16x8 k0 = *(const bf16x8*)&Ks[it][c][kstep*16 + hi*8];
            const bf16x8 k1 = *(const bf16x8*)&Ks[it][32 + c][kstep*16 + hi*8];
            sa0 = __builtin_amdgcn_mfma_f32_32x32x16_bf16(k0, qf[kstep], sa0, 0, 0, 0);
            sa1 = __builtin_amdgcn_mfma_f32_32x32x16_bf16(k1, qf[kstep], sa1, 0, 0, 0);
        }
        __builtin_amdgcn_s_setprio(0);

        // ---- mask add + in-lane max ----
        float mx = -INFINITY;
#pragma unroll
        for (int t = 0; t < 4; t++) {
            const f32x4 ma0 = *(const f32x4*)&madd2[kt +      t*8 + hi*4];
            const f32x4 ma1 = *(const f32x4*)&madd2[kt + 32 + t*8 + hi*4];
#pragma unroll
            for (int j = 0; j < 4; j++) {
                sa0[t*4+j] += ma0[j];
                sa1[t*4+j] += ma1[j];
                mx = fmaxf(mx, fmaxf(sa0[t*4+j], sa1[t*4+j]));
            }
        }
        // lazy defer-max: vote on local max; full reduce only on trigger
        if (!__all(mx <= m_run + 11.54f)) {
            mx = fmaxf(mx, __shfl_xor(mx, 32, 64));
            const float mn = fmaxf(m_run, mx);
            const float corr = __builtin_amdgcn_exp2f(m_run - mn);
            oT0 *= corr; oT1 *= corr; l_run *= corr;
            m_run = mn;
        }

        // ---- exp2 + pack to bf16 pairs (quadrant regs) ----
        float psum = 0.f;
        unsigned int z[2][4][2];
#pragma unroll
        for (int t = 0; t < 4; t++) {
            float p0 = __builtin_amdgcn_exp2f(sa0[t*4+0] - m_run);
            float p1 = __builtin_amdgcn_exp2f(sa0[t*4+1] - m_run);
            float p2 = __builtin_amdgcn_exp2f(sa0[t*4+2] - m_run);
            float p3 = __builtin_amdgcn_exp2f(sa0[t*4+3] - m_run);
            asm("v_cvt_pk_bf16_f32 %0, %1, %2" : "=v"(z[0][t][0]) : "v"(p0), "v"(p1));
            asm("v_cvt_pk_bf16_f32 %0, %1, %2" : "=v"(z[0][t][1]) : "v"(p2), "v"(p3));
            psum += (p0 + p1) + (p2 + p3);
            float q4 = __builtin_amdgcn_exp2f(sa1[t*4+0] - m_run);
            float q5 = __builtin_amdgcn_exp2f(sa1[t*4+1] - m_run);
            float q6 = __builtin_amdgcn_exp2f(sa1[t*4+2] - m_run);
            float q7 = __builtin_amdgcn_exp2f(sa1[t*4+3] - m_run);
            asm("v_cvt_pk_bf16_f32 %0, %1, %2" : "=v"(z[1][t][0]) : "v"(q4), "v"(q5));
            asm("v_cvt_pk_bf16_f32 %0, %1, %2" : "=v"(z[1][t][1]) : "v"(q6), "v"(q7));
            psum += (q4 + q5) + (q6 + q7);
        }
        psum += __shfl_xor(psum, 32, 64);
        l_run += psum;

        // ---- O^T += V^T * P^T  (P^T B-frags via permlane32_swap) ----
        __builtin_amdgcn_s_setprio(1);
#pragma unroll
        for (int kg = 0; kg < 2; kg++) {
#pragma unroll
            for (int ksl = 0; ksl < 2; ksl++) {
                unsigned int a0 = z[kg][2*ksl][0], a1 = z[kg][2*ksl][1];
                unsigned int b0 = z[kg][2*ksl+1][0], b1 = z[kg][2*ksl+1][1];
                asm volatile("v_permlane32_swap_b32 %0, %1" : "+v"(a0), "+v"(b0));
                asm volatile("v_permlane32_swap_b32 %0, %1" : "+v"(a1), "+v"(b1));
                union { unsigned int u[4]; bf16x8 v; } pf;
                pf.u[0] = a0; pf.u[1] = a1; pf.u[2] = b0; pf.u[3] = b1;
                const int kcol = (kg*2 + ksl)*16 + hi*8;
                const bf16x8 v0 = *(const bf16x8*)&Vt[it][c][kcol];
                const bf16x8 v1 = *(const bf16x8*)&Vt[it][32 + c][kcol];
                oT0 = __builtin_amdgcn_mfma_f32_32x32x16_bf16(v0, pf.v, oT0, 0, 0, 0);
                oT1 = __builtin_amdgcn_mfma_f32_32x32x16_bf16(v1, pf.v, oT1, 0, 0, 0);
            }
        }
        __builtin_amdgcn_s_setprio(0);

        // ---- write prefetched tile into the other buffer ----
        if (more) {
            *(bf16x8*)&Ks[it^1][srow][sc0]     = kr0;
            *(bf16x8*)&Ks[it^1][srow][sc0 + 8] = kr1;
            *(bf16x8*)&Vt[it^1][srow][sc0]     = vr0;
            *(bf16x8*)&Vt[it^1][srow][sc0 + 8] = vr1;
        }
    }

    // ---- epilogue: O^T lane-local per query; normalize & store ----
    const float inv = 1.0f / l_run;
    const int s = q0 + w*32 + c;
    bf16* dst = attn + ((size_t)(b*2048) + s) * 512 + h*64;
#pragma unroll
    for (int t = 0; t < 4; t++) {
        bf16x4 o0, o1;
#pragma unroll
        for (int j = 0; j < 4; j++) {
            o0[j] = (bf16)(oT0[t*4+j] * inv);
            o1[j] = (bf16)(oT1[t*4+j] * inv);
        }
        *(bf16x4*)(dst +      t*8 + hi*4) = o0;
        *(bf16x4*)(dst + 32 + t*8 + hi*4) = o1;
    }
}

// ---------------------------------------------------------------------------
extern "C" void kernel_launch(void* const* d_in, const int* in_sizes, int n_in,
                              void* d_out, int out_size, void* d_ws, size_t ws_size,
                              hipStream_t stream)
{
    const float* q    = (const float*)d_in[0];
    const float* k    = (const float*)d_in[1];
    const float* v    = (const float*)d_in[2];
    const int*   mask = (const int*)  d_in[3];
    const float* wq   = (const float*)d_in[4];
    const float* bq   = (const float*)d_in[5];
    const float* wk   = (const float*)d_in[6];
    const float* bk   = (const float*)d_in[7];
    const float* wv   = (const float*)d_in[8];
    const float* bv   = (const float*)d_in[9];
    const float* wd   = (const float*)d_in[10];
    const float* bd   = (const float*)d_in[11];
    float* out = (float*)d_out;

    const size_t NELEM = (size_t)4 * 2048 * 512;   // 4,194,304
    bf16* qp  = (bf16*)d_ws;
    bf16* kp  = qp + NELEM;
    bf16* vpT = kp + NELEM;                         // [B,H,64,S]
    bf16* ab  = vpT + NELEM;                        // merged attn output
    bf16* wt  = ab + NELEM;                         // 4 x 512x512 bf16

    prep_w<<<dim3(8, 8, 4), dim3(256), 0, stream>>>(wq, wk, wv, wd, wt);

    proj_kernel<<<dim3(128, 4, 3), dim3(256), 0, stream>>>(
        q, k, v, wt, bq, bk, bv, qp, kp, vpT);

    attn_kernel<<<dim3(32, 16), dim3(256), 0, stream>>>(qp, kp, vpT, mask, ab);

    dense_kernel<<<dim3(128, 4), dim3(256), 0, stream>>>(
        ab, wt + 3*262144, bd, out);
}